// Round 9
// baseline (883.155 us; speedup 1.0000x reference)
//
#include <hip/hip_runtime.h>

#define NPIX (512*512)

typedef __attribute__((ext_vector_type(8))) short short8;   // 8 bf16 in 4 VGPRs
typedef __attribute__((ext_vector_type(4))) float f32x4;    // MFMA accumulator

#define MFMA16(A, B, C) __builtin_amdgcn_mfma_f32_16x16x32_bf16((A), (B), (C), 0, 0, 0)

// JAX gelu(approximate=True): x * sigmoid(2*sqrt(2/pi)*(x+0.044715x^3)); inf-safe.
__device__ __forceinline__ float gelu_f(float x) {
    return x / (1.0f + __expf(-1.5957691216057308f * (x + 0.044715f * x * x * x)));
}

// f32 -> bf16 bits (RNE)
__device__ __forceinline__ unsigned short bf16_rne(float x) {
    unsigned int b = __float_as_uint(x);
    unsigned int r = b + 0x7fffu + ((b >> 16) & 1u);
    return (unsigned short)(r >> 16);
}
__device__ __forceinline__ float bf16_tof(unsigned short h) {
    return __uint_as_float(((unsigned int)h) << 16);
}
// split x ~= hi + lo (each bf16); dropped cross term in 3-term MFMA ~2^-18 rel.
__device__ __forceinline__ unsigned int bf16_split_pack(float x) {
    unsigned short hi = bf16_rne(x);
    unsigned short lo = bf16_rne(x - bf16_tof(hi));
    return (unsigned int)hi | ((unsigned int)lo << 16);
}
__device__ __forceinline__ void split8(const float* x, short8& h, short8& l) {
    #pragma unroll
    for (int j = 0; j < 8; ++j) {
        unsigned short hi = bf16_rne(x[j]);
        h[j] = (short)hi;
        l[j] = (short)bf16_rne(x[j] - bf16_tof(hi));
    }
}

#define ASLAB ((size_t)16 * 4 * 2 * 64 * 48)   // shorts per (l,ax) in Am

// ---------------------------------------------------------------------------
// Merged setup: blocks 0..15 pack DFT basis tables, 16..31 pack FFN weights,
// 32..287 pack spectral A-weights. All independent; one launch.
// ---------------------------------------------------------------------------
__global__ __launch_bounds__(256) void k_setup(const float* __restrict__ W1, const float* __restrict__ W2,
                                               const float* __restrict__ Are, const float* __restrict__ Aim,
                                               short* __restrict__ FbB, short* __restrict__ GbF,
                                               short* __restrict__ Wpk, short* __restrict__ Am) {
    int b = blockIdx.x;
    int t = threadIdx.x;
    if (b < 16) {
        // FbB: record (kc<16, nt<2, lane): elem j = Fb[kc*32+quad*8+j][nt*16+l15]
        // GbF: record (tt<32, lane): elem j = Gb[tt*16+l15][quad*8+j]
        int id = b * 256 + t;
        int lane = id & 63;
        int quad = lane >> 4, l15 = lane & 15;
        short* dst;
        int n0, nstep, o0, ostep;
        float wscale = 1.0f;
        if (id < 2048) {
            int nt = (id >> 6) & 1, kc = id >> 7;
            dst = FbB + id * 16;
            n0 = kc * 32 + quad * 8; nstep = 1;
            o0 = nt * 16 + l15;      ostep = 0;
        } else {
            int id2 = id - 2048;
            dst = GbF + id2 * 16;
            int tt = id2 >> 6;
            n0 = tt * 16 + l15;      nstep = 0;
            o0 = quad * 8;           ostep = 1;
            wscale = 1.0f / 512.0f;
        }
        #pragma unroll
        for (int j = 0; j < 8; ++j) {
            int n = n0 + nstep * j;
            int o = o0 + ostep * j;
            int m = o >> 1, ri = o & 1;
            int k = (n * m) & 511;
            float sv, cv;
            sincosf(6.283185307179586f * (1.0f / 512.0f) * (float)k, &sv, &cv);
            float v = ri ? -sv : cv;
            if (id >= 2048) v *= (m == 0 ? 1.0f : 2.0f) * wscale;
            unsigned short hi = bf16_rne(v);
            dst[j]     = (short)hi;
            dst[8 + j] = (short)bf16_rne(v - bf16_tof(hi));
        }
    } else if (b < 32) {
        int tid = (b - 16) * 256 + t;
        int lane = tid & 63;
        int kc = (tid >> 6) & 1;
        int mt = (tid >> 7) & 3;
        int wg = tid >> 9;
        int layer = wg >> 1, which = wg & 1;
        const float* Wsrc = (which ? W2 : W1) + (size_t)layer * 4096;
        int o  = mt * 16 + (lane & 15);
        int c0 = kc * 32 + ((lane >> 4) & 3) * 8;
        short* dst = Wpk + (size_t)tid * 16;
        #pragma unroll
        for (int j = 0; j < 8; ++j) {
            float x = Wsrc[o * 64 + c0 + j];
            unsigned short hi = bf16_rne(x);
            dst[j]     = (short)hi;
            dst[8 + j] = (short)bf16_rne(x - bf16_tof(hi));
        }
    } else {
        // spectral A -> mix A-frag records of 48 shorts: [Ar_h8|Ar_l8|Ai_h8|Ai_l8|An_h8|An_l8]
        int id = (b - 32) * 256 + t;
        int lane = id & 63;
        int kc  = (id >> 6) & 1;
        int mt  = (id >> 7) & 3;
        int m   = (id >> 9) & 15;
        int lax = id >> 13;
        int l = lax >> 1, ax = lax & 1;
        int o  = mt * 16 + (lane & 15);
        int i0 = kc * 32 + ((lane >> 4) & 3) * 8;
        short* dst = Am + (size_t)id * 48;
        #pragma unroll
        for (int j = 0; j < 8; ++j) {
            size_t src = (((size_t)(l * 64 + o) * 64 + (i0 + j)) * 16 + m) * 2 + ax;
            float ar = Are[src], ai = Aim[src];
            unsigned short hh;
            hh = bf16_rne(ar);  dst[j]      = (short)hh; dst[8 + j]  = (short)bf16_rne(ar - bf16_tof(hh));
            hh = bf16_rne(ai);  dst[16 + j] = (short)hh; dst[24 + j] = (short)bf16_rne(ai - bf16_tof(hh));
            hh = bf16_rne(-ai); dst[32 + j] = (short)hh; dst[40 + j] = (short)bf16_rne(-ai - bf16_tof(hh));
        }
    }
}

// Encoder
__global__ __launch_bounds__(256) void k_enc(const float* __restrict__ u, const float* __restrict__ xc,
                                             const float* __restrict__ We, const float* __restrict__ be,
                                             float* __restrict__ h) {
    int pix = blockIdx.x * 256 + threadIdx.x;
    float x0 = xc[pix], x1 = xc[NPIX + pix], uu = u[pix];
    #pragma unroll 8
    for (int p = 0; p < 64; ++p) {
        h[(size_t)p * NPIX + pix] = We[p * 3] * x0 + We[p * 3 + 1] * x1 + We[p * 3 + 2] * uu + be[p];
    }
}

// ---------------------------------------------------------------------------
// Merged forward DFT, both axes, full K=512 per block:
//   axis 0 (H): VfH[p][o][w] = sum_y Fb[y][o]*h[p][y][w]   (B = h columns)
//   axis 1 (W): VfW[p][o][y] = sum_w Fb[w][o]*h[p][y][w]   (B = h rows)
// grid(8 ntile, 64 p, 2 axis), block 256; axis branch is block-uniform.
// ---------------------------------------------------------------------------
__global__ __launch_bounds__(256) void k_fwd(const float* __restrict__ h, const short* __restrict__ FbB,
                                             float* __restrict__ VfH, float* __restrict__ VfW) {
    int t = threadIdx.x;
    int ntb = blockIdx.x, p = blockIdx.y, axis = blockIdx.z;
    int wv = t >> 6, lane = t & 63, quad = lane >> 4, l15 = lane & 15;
    int n = ntb * 64 + wv * 16 + l15;
    f32x4 acc[2];
    acc[0] = (f32x4){0.f,0.f,0.f,0.f}; acc[1] = (f32x4){0.f,0.f,0.f,0.f};
    #pragma unroll 4
    for (int kc = 0; kc < 16; ++kc) {
        int kb = kc * 32 + quad * 8;
        float bv[8];
        if (axis == 0) {
            const float* hp = h + ((size_t)p * 512 + kb) * 512 + n;
            #pragma unroll
            for (int j = 0; j < 8; ++j) bv[j] = hp[(size_t)j * 512];
        } else {
            const float* hp = h + ((size_t)p * 512 + n) * 512 + kb;
            float4 x0 = *(const float4*)hp;
            float4 x1 = *(const float4*)(hp + 4);
            bv[0]=x0.x; bv[1]=x0.y; bv[2]=x0.z; bv[3]=x0.w;
            bv[4]=x1.x; bv[5]=x1.y; bv[6]=x1.z; bv[7]=x1.w;
        }
        short8 Bh, Bl; split8(bv, Bh, Bl);
        #pragma unroll
        for (int mt = 0; mt < 2; ++mt) {
            const short8* ap = (const short8*)(FbB + (((kc * 2 + mt) * 64 + lane) << 4));
            short8 Ah = ap[0], Al = ap[1];
            acc[mt] = MFMA16(Ah, Bh, acc[mt]);
            acc[mt] = MFMA16(Al, Bh, acc[mt]);
            acc[mt] = MFMA16(Ah, Bl, acc[mt]);
        }
    }
    float* vp = (axis ? VfW : VfH) + (size_t)p * 32 * 512;
    #pragma unroll
    for (int mt = 0; mt < 2; ++mt)
        #pragma unroll
        for (int r = 0; r < 4; ++r)
            vp[(size_t)(mt * 16 + quad * 4 + r) * 512 + n] = acc[mt][r];
}

// ---------------------------------------------------------------------------
// Merged mode mixing, both axes: D_re = Ar.Br + An.Bi, D_im = Ar.Bi + Ai.Br.
// grid 512 (axis = bid>>8; m = bid&15, otile = (bid>>4)&15), block 256.
// ---------------------------------------------------------------------------
__global__ __launch_bounds__(256) void k_mix2(const float* __restrict__ VfH, const float* __restrict__ VfW,
                                              const short* __restrict__ AmL,
                                              float* __restrict__ VmH, float* __restrict__ VmW) {
    __shared__ unsigned int BT[2 * 64 * 33];
    int bid = blockIdx.x;
    int axis = bid >> 8;
    int m  = bid & 15;
    int ot = (bid >> 4) & 15;
    const float* Vf = axis ? VfW : VfH;
    float* Vm = axis ? VmW : VmH;
    const short* Am = AmL + (size_t)axis * ASLAB;
    int t = threadIdx.x;
    #pragma unroll
    for (int it = 0; it < 16; ++it) {
        int idx = it * 256 + t;
        int oth = idx & 31, ri = (idx >> 5) & 1, i = idx >> 6;
        float v = Vf[((size_t)i * 32 + m * 2 + ri) * 512 + ot * 32 + oth];
        BT[(ri * 64 + i) * 33 + oth] = bf16_split_pack(v);
    }
    __syncthreads();
    int wv = t >> 6, lane = t & 63, quad = lane >> 4, l15 = lane & 15;
    int nt = wv & 1, mtp = wv >> 1;
    f32x4 aR[2], aI[2];
    aR[0]=(f32x4){0.f,0.f,0.f,0.f}; aR[1]=aR[0]; aI[0]=aR[0]; aI[1]=aR[0];
    #pragma unroll
    for (int kc = 0; kc < 2; ++kc) {
        short8 Brh, Brl, Bih, Bil;
        #pragma unroll
        for (int j = 0; j < 8; ++j) {
            int i = kc * 32 + quad * 8 + j;
            unsigned int br = BT[i * 33 + nt * 16 + l15];
            unsigned int bi = BT[(64 + i) * 33 + nt * 16 + l15];
            Brh[j] = (short)(br & 0xffffu); Brl[j] = (short)(br >> 16);
            Bih[j] = (short)(bi & 0xffffu); Bil[j] = (short)(bi >> 16);
        }
        #pragma unroll
        for (int mi = 0; mi < 2; ++mi) {
            int mt = mtp * 2 + mi;
            const short8* ap = (const short8*)(Am + ((size_t)(((m * 4 + mt) * 2 + kc) * 64 + lane)) * 48);
            short8 Arh = ap[0], Arl = ap[1], Aih = ap[2], Ail = ap[3], Anh = ap[4], Anl = ap[5];
            aR[mi] = MFMA16(Arh, Brh, aR[mi]);
            aR[mi] = MFMA16(Arl, Brh, aR[mi]);
            aR[mi] = MFMA16(Arh, Brl, aR[mi]);
            aR[mi] = MFMA16(Anh, Bih, aR[mi]);
            aR[mi] = MFMA16(Anl, Bih, aR[mi]);
            aR[mi] = MFMA16(Anh, Bil, aR[mi]);
            aI[mi] = MFMA16(Arh, Bih, aI[mi]);
            aI[mi] = MFMA16(Arl, Bih, aI[mi]);
            aI[mi] = MFMA16(Arh, Bil, aI[mi]);
            aI[mi] = MFMA16(Aih, Brh, aI[mi]);
            aI[mi] = MFMA16(Ail, Brh, aI[mi]);
            aI[mi] = MFMA16(Aih, Brl, aI[mi]);
        }
    }
    int oth = ot * 32 + nt * 16 + l15;
    #pragma unroll
    for (int mi = 0; mi < 2; ++mi) {
        int o = (mtp * 2 + mi) * 16 + quad * 4;
        #pragma unroll
        for (int r = 0; r < 4; ++r) {
            float2 v; v.x = aR[mi][r]; v.y = aI[mi][r];
            *(float2*)(Vm + ((size_t)(o + r) * 512 + oth) * 32 + m * 2) = v;
        }
    }
}

// ---------------------------------------------------------------------------
// Fused inverse DFT (both axes) -> s as PLAIN BF16 (2 B).
// grid(8 wt, 8 yt, 64 p), block 256.
// ---------------------------------------------------------------------------
__global__ __launch_bounds__(256) void k_inv(const float* __restrict__ VmW, const float* __restrict__ VmH,
                                             const short* __restrict__ GbF, unsigned short* __restrict__ s) {
    int t = threadIdx.x;
    int wt = blockIdx.x, yt = blockIdx.y, p = blockIdx.z;
    int wv = t >> 6, lane = t & 63, quad = lane >> 4, l15 = lane & 15;
    int ys = yt * 64 + wv * 16;
    const float* a2p = VmW + ((size_t)p * 512 + ys + l15) * 32 + quad * 8;
    float av[8];
    {
        float4 x0 = *(const float4*)a2p;
        float4 x1 = *(const float4*)(a2p + 4);
        av[0]=x0.x; av[1]=x0.y; av[2]=x0.z; av[3]=x0.w;
        av[4]=x1.x; av[5]=x1.y; av[6]=x1.z; av[7]=x1.w;
    }
    short8 A2h, A2l; split8(av, A2h, A2l);
    const short8* g1 = (const short8*)(GbF + (((yt * 4 + wv) * 64 + lane) << 4));
    short8 A1h = g1[0], A1l = g1[1];
    #pragma unroll
    for (int nt = 0; nt < 4; ++nt) {
        int wb = wt * 64 + nt * 16;
        const float* b1p = VmH + ((size_t)p * 512 + wb + l15) * 32 + quad * 8;
        float bv[8];
        float4 x0 = *(const float4*)b1p;
        float4 x1 = *(const float4*)(b1p + 4);
        bv[0]=x0.x; bv[1]=x0.y; bv[2]=x0.z; bv[3]=x0.w;
        bv[4]=x1.x; bv[5]=x1.y; bv[6]=x1.z; bv[7]=x1.w;
        short8 B1h, B1l; split8(bv, B1h, B1l);
        const short8* g2 = (const short8*)(GbF + (((wt * 4 + nt) * 64 + lane) << 4));
        short8 B2h = g2[0], B2l = g2[1];
        f32x4 acc = (f32x4){0.f,0.f,0.f,0.f};
        acc = MFMA16(A1h, B1h, acc);
        acc = MFMA16(A1l, B1h, acc);
        acc = MFMA16(A1h, B1l, acc);
        acc = MFMA16(A2h, B2h, acc);
        acc = MFMA16(A2l, B2h, acc);
        acc = MFMA16(A2h, B2l, acc);
        #pragma unroll
        for (int r = 0; r < 4; ++r)
            s[((size_t)p * 512 + ys + quad * 4 + r) * 512 + wb + l15] = bf16_rne(acc[r]);
    }
}

// ---------------------------------------------------------------------------
// MFMA FFN, 4 tiles/block: h[o][pix] += gelu(W2.gelu(W1.s+b1)+b2).
// W1 frags preloaded ONCE per block (4x amortization). Per tile: s loads +
// h-residual prefetch (independent -> latency overlaps staging/GEMM1/GEMM2).
// sB stride 33 (staging writes 2-way/free, frag b32 reads <=4-way); GEMM1 is
// 2-term (s is bf16); tT XOR-swizzled; oT aliases sB. LDS 33792 B.
// ---------------------------------------------------------------------------
union FfnSmem {
    unsigned int sB[64 * 33];   // 8448 B, staged bf16 s tile [pix][ch-pair]
    float oT[64 * 68];          // 17408 B, epilogue2 transpose tile
};

__global__ __launch_bounds__(256, 4) void k_ffn2m(const unsigned short* __restrict__ in, float* __restrict__ out,
                                                  const short* __restrict__ w1f, const float* __restrict__ b1v,
                                                  const short* __restrict__ w2f, const float* __restrict__ b2v) {
    __shared__ __align__(16) FfnSmem u;
    __shared__ __align__(16) unsigned int tT[64 * 64];
    int t = threadIdx.x;
    int lane15 = t & 15;
    int quad   = (t >> 4) & 3;
    int wv     = t >> 6;
    int row    = wv * 16 + lane15;
    int k  = t >> 3;                           // staging channel pair 0..31
    int po = t & 7;                            // staging pixel oct
    int pix0 = (t & 15) * 4;                   // RMW pixel base
    int c0 = (t >> 4) * 4;                     // RMW channel base

    // ---- W1 frags: loaded once, live across all 4 tiles ----
    short8 W1h[8], W1l[8];
    #pragma unroll
    for (int s8 = 0; s8 < 8; ++s8) {
        const short8* p = (const short8*)(w1f + (((size_t)s8 * 64 + (t & 63)) << 4));
        W1h[s8] = p[0]; W1l[s8] = p[1];
    }

    #pragma unroll 1
    for (int tile = 0; tile < 4; ++tile) {
        int pixBase = (blockIdx.x * 4 + tile) * 64;

        // ---- issue independent loads up front: s tile + h residual prefetch ----
        const uint4* r0 = (const uint4*)(in + (size_t)(2 * k) * NPIX + pixBase) + po;
        const uint4* r1 = (const uint4*)(in + (size_t)(2 * k + 1) * NPIX + pixBase) + po;
        uint4 a = *r0, b = *r1;
        float4 hres[4];
        #pragma unroll
        for (int i = 0; i < 4; ++i)
            hres[i] = *(const float4*)(out + (size_t)(c0 + i) * NPIX + pixBase + pix0);

        {
            unsigned int aw[4] = {a.x, a.y, a.z, a.w};
            unsigned int bw[4] = {b.x, b.y, b.z, b.w};
            #pragma unroll
            for (int i = 0; i < 4; ++i) {
                int pix = po * 8 + 2 * i;
                u.sB[pix * 33 + k]       = (aw[i] & 0xffffu) | (bw[i] << 16);
                u.sB[(pix + 1) * 33 + k] = (aw[i] >> 16) | (bw[i] & 0xffff0000u);
            }
        }

        f32x4 acc[4];
        #pragma unroll
        for (int mt = 0; mt < 4; ++mt) acc[mt] = (f32x4){0.f, 0.f, 0.f, 0.f};

        __syncthreads();

        // ---- GEMM1: 2-term (s is bf16) ----
        #pragma unroll
        for (int kc = 0; kc < 2; ++kc) {
            union { unsigned int w[4]; short8 v; } bb;
            #pragma unroll
            for (int i = 0; i < 4; ++i)
                bb.w[i] = u.sB[row * 33 + kc * 16 + quad * 4 + i];
            #pragma unroll
            for (int mt = 0; mt < 4; ++mt) {
                int s8 = mt * 2 + kc;
                acc[mt] = MFMA16(W1h[s8], bb.v, acc[mt]);
                acc[mt] = MFMA16(W1l[s8], bb.v, acc[mt]);
            }
        }

        // ---- epilogue1: gelu, split, write tT ----
        #pragma unroll
        for (int mt = 0; mt < 4; ++mt) {
            const float* bp = b1v + mt * 16 + quad * 4;
            unsigned int pk[4];
            #pragma unroll
            for (int r = 0; r < 4; ++r) {
                float g = gelu_f(acc[mt][r] + bp[r]);
                pk[r] = bf16_split_pack(g);
            }
            int cg = mt * 4 + quad;
            unsigned int* dst = &tT[row * 64 + ((cg ^ lane15) << 2)];
            *(uint4*)dst = make_uint4(pk[0], pk[1], pk[2], pk[3]);
            acc[mt] = (f32x4){0.f, 0.f, 0.f, 0.f};
        }

        short8 W2h[8], W2l[8];
        #pragma unroll
        for (int s8 = 0; s8 < 8; ++s8) {
            const short8* p = (const short8*)(w2f + (((size_t)s8 * 64 + (t & 63)) << 4));
            W2h[s8] = p[0]; W2l[s8] = p[1];
        }

        __syncthreads();   // tT visible; also fences GEMM1 sB reads (oT may alias)

        // ---- GEMM2: 3-term (t stays split) ----
        #pragma unroll
        for (int kc = 0; kc < 2; ++kc) {
            int cg0 = kc * 8 + quad * 2;
            uint4 u0 = *(const uint4*)&tT[row * 64 + ((cg0 ^ lane15) << 2)];
            uint4 u1 = *(const uint4*)&tT[row * 64 + (((cg0 + 1) ^ lane15) << 2)];
            union { unsigned int w[4]; short8 v; } bh, bl;
            bh.w[0] = (u0.x & 0xffffu) | (u0.y << 16);
            bh.w[1] = (u0.z & 0xffffu) | (u0.w << 16);
            bh.w[2] = (u1.x & 0xffffu) | (u1.y << 16);
            bh.w[3] = (u1.z & 0xffffu) | (u1.w << 16);
            bl.w[0] = (u0.x >> 16) | (u0.y & 0xffff0000u);
            bl.w[1] = (u0.z >> 16) | (u0.w & 0xffff0000u);
            bl.w[2] = (u1.x >> 16) | (u1.y & 0xffff0000u);
            bl.w[3] = (u1.z >> 16) | (u1.w & 0xffff0000u);
            #pragma unroll
            for (int mt = 0; mt < 4; ++mt) {
                int s8 = mt * 2 + kc;
                acc[mt] = MFMA16(W2h[s8], bh.v, acc[mt]);
                acc[mt] = MFMA16(W2h[s8], bl.v, acc[mt]);
                acc[mt] = MFMA16(W2l[s8], bh.v, acc[mt]);
            }
        }

        // ---- epilogue2: gelu -> oT (aliases sB), then float4 h store w/ prefetched residual ----
        #pragma unroll
        for (int mt = 0; mt < 4; ++mt) {
            const float* bp = b2v + mt * 16 + quad * 4;
            #pragma unroll
            for (int r = 0; r < 4; ++r) {
                int o = mt * 16 + quad * 4 + r;
                u.oT[o * 68 + row] = gelu_f(acc[mt][r] + bp[r]);
            }
        }
        __syncthreads();
        #pragma unroll
        for (int i = 0; i < 4; ++i) {
            int c = c0 + i;
            float4 gv = *(const float4*)&u.oT[c * 68 + pix0];
            float4 cur = hres[i];
            cur.x += gv.x; cur.y += gv.y; cur.z += gv.z; cur.w += gv.w;
            *(float4*)(out + (size_t)c * NPIX + pixBase + pix0) = cur;
        }
        __syncthreads();   // oT reads done before next tile's sB staging writes
    }
}

// Decoder
__global__ __launch_bounds__(256) void k_dec(const float* __restrict__ h, const float* __restrict__ Wd,
                                             const float* __restrict__ bd, float* __restrict__ out) {
    int pix = blockIdx.x * 256 + threadIdx.x;
    float acc = bd[0];
    #pragma unroll 8
    for (int c = 0; c < 64; ++c) acc += Wd[c] * h[(size_t)c * NPIX + pix];
    out[pix] = acc;
}

extern "C" void kernel_launch(void* const* d_in, const int* in_sizes, int n_in,
                              void* d_out, int out_size, void* d_ws, size_t ws_size,
                              hipStream_t stream) {
    (void)in_sizes; (void)n_in; (void)out_size; (void)ws_size;
    const float* u   = (const float*)d_in[0];
    const float* xc  = (const float*)d_in[1];
    const float* We  = (const float*)d_in[2];
    const float* be  = (const float*)d_in[3];
    const float* W1  = (const float*)d_in[4];
    const float* b1  = (const float*)d_in[5];
    const float* W2  = (const float*)d_in[6];
    const float* b2  = (const float*)d_in[7];
    const float* Are = (const float*)d_in[8];
    const float* Aim = (const float*)d_in[9];
    const float* Wd  = (const float*)d_in[10];
    const float* bd  = (const float*)d_in[11];

    // workspace layout (float units), ~125 MB used
    float* ws  = (float*)d_ws;
    float* h   = ws;                            // 64 MB
    unsigned short* s = (unsigned short*)(h + (size_t)16777216);  // 32 MB (bf16), 64 MB slot
    float* VfH = (float*)((char*)s + (size_t)67108864); // 4 MB: [64][32][512]
    float* VfW = VfH + (size_t)1048576;         // 4 MB
    float* VmH = VfW + (size_t)1048576;         // 4 MB: [64][512][32]
    float* VmW = VmH + (size_t)1048576;         // 4 MB
    short* FbB = (short*)(VmW + 1048576);       // 64 KB
    short* GbF = FbB + 32768;                   // 64 KB
    short* Am  = GbF + 32768;                   // 6 MB: 65536 rec x 48 shorts
    short* Wpk = Am  + (size_t)65536 * 48;      // 128 KB

    k_setup<<<288, 256, 0, stream>>>(W1, W2, Are, Aim, FbB, GbF, Wpk, Am);
    k_enc<<<1024, 256, 0, stream>>>(u, xc, We, be, h);

    for (int l = 0; l < 4; ++l) {
        k_fwd<<<dim3(8, 64, 2), 256, 0, stream>>>(h, FbB, VfH, VfW);
        k_mix2<<<512, 256, 0, stream>>>(VfH, VfW, Am + (size_t)(l * 2) * ASLAB, VmH, VmW);
        k_inv<<<dim3(8, 8, 64), 256, 0, stream>>>(VmW, VmH, GbF, s);
        k_ffn2m<<<1024, 256, 0, stream>>>(s, h,
                                          Wpk + (size_t)(l * 2 + 0) * 8192, b1 + (size_t)l * 64,
                                          Wpk + (size_t)(l * 2 + 1) * 8192, b2 + (size_t)l * 64);
    }
    k_dec<<<1024, 256, 0, stream>>>(h, Wd, bd, (float*)d_out);
}

// Round 10
// 548.651 us; speedup vs baseline: 1.6097x; 1.6097x over previous
//
#include <hip/hip_runtime.h>

#define NPIX (512*512)

typedef __attribute__((ext_vector_type(8))) short short8;   // 8 bf16 in 4 VGPRs
typedef __attribute__((ext_vector_type(4))) float f32x4;    // MFMA accumulator

#define MFMA16(A, B, C) __builtin_amdgcn_mfma_f32_16x16x32_bf16((A), (B), (C), 0, 0, 0)

// JAX gelu(approximate=True): x * sigmoid(2*sqrt(2/pi)*(x+0.044715x^3)); inf-safe.
__device__ __forceinline__ float gelu_f(float x) {
    return x / (1.0f + __expf(-1.5957691216057308f * (x + 0.044715f * x * x * x)));
}

// f32 -> bf16 bits (RNE)
__device__ __forceinline__ unsigned short bf16_rne(float x) {
    unsigned int b = __float_as_uint(x);
    unsigned int r = b + 0x7fffu + ((b >> 16) & 1u);
    return (unsigned short)(r >> 16);
}
__device__ __forceinline__ float bf16_tof(unsigned short h) {
    return __uint_as_float(((unsigned int)h) << 16);
}
// split x ~= hi + lo (each bf16); dropped cross term in 3-term MFMA ~2^-18 rel.
__device__ __forceinline__ unsigned int bf16_split_pack(float x) {
    unsigned short hi = bf16_rne(x);
    unsigned short lo = bf16_rne(x - bf16_tof(hi));
    return (unsigned int)hi | ((unsigned int)lo << 16);
}
__device__ __forceinline__ void split8(const float* x, short8& h, short8& l) {
    #pragma unroll
    for (int j = 0; j < 8; ++j) {
        unsigned short hi = bf16_rne(x[j]);
        h[j] = (short)hi;
        l[j] = (short)bf16_rne(x[j] - bf16_tof(hi));
    }
}

#define ASLAB ((size_t)16 * 4 * 2 * 64 * 48)   // shorts per (l,ax) in Am

// ---------------------------------------------------------------------------
// Merged setup: blocks 0..15 pack DFT basis tables, 16..31 pack FFN weights,
// 32..287 pack spectral A-weights. All independent; one launch.
// ---------------------------------------------------------------------------
__global__ __launch_bounds__(256) void k_setup(const float* __restrict__ W1, const float* __restrict__ W2,
                                               const float* __restrict__ Are, const float* __restrict__ Aim,
                                               short* __restrict__ FbB, short* __restrict__ GbF,
                                               short* __restrict__ Wpk, short* __restrict__ Am) {
    int b = blockIdx.x;
    int t = threadIdx.x;
    if (b < 16) {
        // FbB: record (kc<16, nt<2, lane): elem j = Fb[kc*32+quad*8+j][nt*16+l15]
        // GbF: record (tt<32, lane): elem j = Gb[tt*16+l15][quad*8+j]
        int id = b * 256 + t;
        int lane = id & 63;
        int quad = lane >> 4, l15 = lane & 15;
        short* dst;
        int n0, nstep, o0, ostep;
        float wscale = 1.0f;
        if (id < 2048) {
            int nt = (id >> 6) & 1, kc = id >> 7;
            dst = FbB + id * 16;
            n0 = kc * 32 + quad * 8; nstep = 1;
            o0 = nt * 16 + l15;      ostep = 0;
        } else {
            int id2 = id - 2048;
            dst = GbF + id2 * 16;
            int tt = id2 >> 6;
            n0 = tt * 16 + l15;      nstep = 0;
            o0 = quad * 8;           ostep = 1;
            wscale = 1.0f / 512.0f;
        }
        #pragma unroll
        for (int j = 0; j < 8; ++j) {
            int n = n0 + nstep * j;
            int o = o0 + ostep * j;
            int m = o >> 1, ri = o & 1;
            int k = (n * m) & 511;
            float sv, cv;
            sincosf(6.283185307179586f * (1.0f / 512.0f) * (float)k, &sv, &cv);
            float v = ri ? -sv : cv;
            if (id >= 2048) v *= (m == 0 ? 1.0f : 2.0f) * wscale;
            unsigned short hi = bf16_rne(v);
            dst[j]     = (short)hi;
            dst[8 + j] = (short)bf16_rne(v - bf16_tof(hi));
        }
    } else if (b < 32) {
        int tid = (b - 16) * 256 + t;
        int lane = tid & 63;
        int kc = (tid >> 6) & 1;
        int mt = (tid >> 7) & 3;
        int wg = tid >> 9;
        int layer = wg >> 1, which = wg & 1;
        const float* Wsrc = (which ? W2 : W1) + (size_t)layer * 4096;
        int o  = mt * 16 + (lane & 15);
        int c0 = kc * 32 + ((lane >> 4) & 3) * 8;
        short* dst = Wpk + (size_t)tid * 16;
        #pragma unroll
        for (int j = 0; j < 8; ++j) {
            float x = Wsrc[o * 64 + c0 + j];
            unsigned short hi = bf16_rne(x);
            dst[j]     = (short)hi;
            dst[8 + j] = (short)bf16_rne(x - bf16_tof(hi));
        }
    } else {
        // spectral A -> mix A-frag records of 48 shorts: [Ar_h8|Ar_l8|Ai_h8|Ai_l8|An_h8|An_l8]
        int id = (b - 32) * 256 + t;
        int lane = id & 63;
        int kc  = (id >> 6) & 1;
        int mt  = (id >> 7) & 3;
        int m   = (id >> 9) & 15;
        int lax = id >> 13;
        int l = lax >> 1, ax = lax & 1;
        int o  = mt * 16 + (lane & 15);
        int i0 = kc * 32 + ((lane >> 4) & 3) * 8;
        short* dst = Am + (size_t)id * 48;
        #pragma unroll
        for (int j = 0; j < 8; ++j) {
            size_t src = (((size_t)(l * 64 + o) * 64 + (i0 + j)) * 16 + m) * 2 + ax;
            float ar = Are[src], ai = Aim[src];
            unsigned short hh;
            hh = bf16_rne(ar);  dst[j]      = (short)hh; dst[8 + j]  = (short)bf16_rne(ar - bf16_tof(hh));
            hh = bf16_rne(ai);  dst[16 + j] = (short)hh; dst[24 + j] = (short)bf16_rne(ai - bf16_tof(hh));
            hh = bf16_rne(-ai); dst[32 + j] = (short)hh; dst[40 + j] = (short)bf16_rne(-ai - bf16_tof(hh));
        }
    }
}

// Encoder
__global__ __launch_bounds__(256) void k_enc(const float* __restrict__ u, const float* __restrict__ xc,
                                             const float* __restrict__ We, const float* __restrict__ be,
                                             float* __restrict__ h) {
    int pix = blockIdx.x * 256 + threadIdx.x;
    float x0 = xc[pix], x1 = xc[NPIX + pix], uu = u[pix];
    #pragma unroll 8
    for (int p = 0; p < 64; ++p) {
        h[(size_t)p * NPIX + pix] = We[p * 3] * x0 + We[p * 3 + 1] * x1 + We[p * 3 + 2] * uu + be[p];
    }
}

// ---------------------------------------------------------------------------
// Merged forward DFT, both axes, full K=512 per block:
//   axis 0 (H): VfH[p][o][w] = sum_y Fb[y][o]*h[p][y][w]   (B = h columns)
//   axis 1 (W): VfW[p][o][y] = sum_w Fb[w][o]*h[p][y][w]   (B = h rows)
// grid(8 ntile, 64 p, 2 axis), block 256; axis branch is block-uniform.
// ---------------------------------------------------------------------------
__global__ __launch_bounds__(256) void k_fwd(const float* __restrict__ h, const short* __restrict__ FbB,
                                             float* __restrict__ VfH, float* __restrict__ VfW) {
    int t = threadIdx.x;
    int ntb = blockIdx.x, p = blockIdx.y, axis = blockIdx.z;
    int wv = t >> 6, lane = t & 63, quad = lane >> 4, l15 = lane & 15;
    int n = ntb * 64 + wv * 16 + l15;
    f32x4 acc[2];
    acc[0] = (f32x4){0.f,0.f,0.f,0.f}; acc[1] = (f32x4){0.f,0.f,0.f,0.f};
    #pragma unroll 4
    for (int kc = 0; kc < 16; ++kc) {
        int kb = kc * 32 + quad * 8;
        float bv[8];
        if (axis == 0) {
            const float* hp = h + ((size_t)p * 512 + kb) * 512 + n;
            #pragma unroll
            for (int j = 0; j < 8; ++j) bv[j] = hp[(size_t)j * 512];
        } else {
            const float* hp = h + ((size_t)p * 512 + n) * 512 + kb;
            float4 x0 = *(const float4*)hp;
            float4 x1 = *(const float4*)(hp + 4);
            bv[0]=x0.x; bv[1]=x0.y; bv[2]=x0.z; bv[3]=x0.w;
            bv[4]=x1.x; bv[5]=x1.y; bv[6]=x1.z; bv[7]=x1.w;
        }
        short8 Bh, Bl; split8(bv, Bh, Bl);
        #pragma unroll
        for (int mt = 0; mt < 2; ++mt) {
            const short8* ap = (const short8*)(FbB + (((kc * 2 + mt) * 64 + lane) << 4));
            short8 Ah = ap[0], Al = ap[1];
            acc[mt] = MFMA16(Ah, Bh, acc[mt]);
            acc[mt] = MFMA16(Al, Bh, acc[mt]);
            acc[mt] = MFMA16(Ah, Bl, acc[mt]);
        }
    }
    float* vp = (axis ? VfW : VfH) + (size_t)p * 32 * 512;
    #pragma unroll
    for (int mt = 0; mt < 2; ++mt)
        #pragma unroll
        for (int r = 0; r < 4; ++r)
            vp[(size_t)(mt * 16 + quad * 4 + r) * 512 + n] = acc[mt][r];
}

// ---------------------------------------------------------------------------
// Merged mode mixing, both axes: D_re = Ar.Br + An.Bi, D_im = Ar.Bi + Ai.Br.
// grid 512 (axis = bid>>8; m = bid&15, otile = (bid>>4)&15), block 256.
// ---------------------------------------------------------------------------
__global__ __launch_bounds__(256) void k_mix2(const float* __restrict__ VfH, const float* __restrict__ VfW,
                                              const short* __restrict__ AmL,
                                              float* __restrict__ VmH, float* __restrict__ VmW) {
    __shared__ unsigned int BT[2 * 64 * 33];
    int bid = blockIdx.x;
    int axis = bid >> 8;
    int m  = bid & 15;
    int ot = (bid >> 4) & 15;
    const float* Vf = axis ? VfW : VfH;
    float* Vm = axis ? VmW : VmH;
    const short* Am = AmL + (size_t)axis * ASLAB;
    int t = threadIdx.x;
    #pragma unroll
    for (int it = 0; it < 16; ++it) {
        int idx = it * 256 + t;
        int oth = idx & 31, ri = (idx >> 5) & 1, i = idx >> 6;
        float v = Vf[((size_t)i * 32 + m * 2 + ri) * 512 + ot * 32 + oth];
        BT[(ri * 64 + i) * 33 + oth] = bf16_split_pack(v);
    }
    __syncthreads();
    int wv = t >> 6, lane = t & 63, quad = lane >> 4, l15 = lane & 15;
    int nt = wv & 1, mtp = wv >> 1;
    f32x4 aR[2], aI[2];
    aR[0]=(f32x4){0.f,0.f,0.f,0.f}; aR[1]=aR[0]; aI[0]=aR[0]; aI[1]=aR[0];
    #pragma unroll
    for (int kc = 0; kc < 2; ++kc) {
        short8 Brh, Brl, Bih, Bil;
        #pragma unroll
        for (int j = 0; j < 8; ++j) {
            int i = kc * 32 + quad * 8 + j;
            unsigned int br = BT[i * 33 + nt * 16 + l15];
            unsigned int bi = BT[(64 + i) * 33 + nt * 16 + l15];
            Brh[j] = (short)(br & 0xffffu); Brl[j] = (short)(br >> 16);
            Bih[j] = (short)(bi & 0xffffu); Bil[j] = (short)(bi >> 16);
        }
        #pragma unroll
        for (int mi = 0; mi < 2; ++mi) {
            int mt = mtp * 2 + mi;
            const short8* ap = (const short8*)(Am + ((size_t)(((m * 4 + mt) * 2 + kc) * 64 + lane)) * 48);
            short8 Arh = ap[0], Arl = ap[1], Aih = ap[2], Ail = ap[3], Anh = ap[4], Anl = ap[5];
            aR[mi] = MFMA16(Arh, Brh, aR[mi]);
            aR[mi] = MFMA16(Arl, Brh, aR[mi]);
            aR[mi] = MFMA16(Arh, Brl, aR[mi]);
            aR[mi] = MFMA16(Anh, Bih, aR[mi]);
            aR[mi] = MFMA16(Anl, Bih, aR[mi]);
            aR[mi] = MFMA16(Anh, Bil, aR[mi]);
            aI[mi] = MFMA16(Arh, Bih, aI[mi]);
            aI[mi] = MFMA16(Arl, Bih, aI[mi]);
            aI[mi] = MFMA16(Arh, Bil, aI[mi]);
            aI[mi] = MFMA16(Aih, Brh, aI[mi]);
            aI[mi] = MFMA16(Ail, Brh, aI[mi]);
            aI[mi] = MFMA16(Aih, Brl, aI[mi]);
        }
    }
    int oth = ot * 32 + nt * 16 + l15;
    #pragma unroll
    for (int mi = 0; mi < 2; ++mi) {
        int o = (mtp * 2 + mi) * 16 + quad * 4;
        #pragma unroll
        for (int r = 0; r < 4; ++r) {
            float2 v; v.x = aR[mi][r]; v.y = aI[mi][r];
            *(float2*)(Vm + ((size_t)(o + r) * 512 + oth) * 32 + m * 2) = v;
        }
    }
}

// ---------------------------------------------------------------------------
// Fused inverse DFT (both axes) -> s as PLAIN BF16 (2 B).
// grid(8 wt, 8 yt, 64 p), block 256.
// ---------------------------------------------------------------------------
__global__ __launch_bounds__(256) void k_inv(const float* __restrict__ VmW, const float* __restrict__ VmH,
                                             const short* __restrict__ GbF, unsigned short* __restrict__ s) {
    int t = threadIdx.x;
    int wt = blockIdx.x, yt = blockIdx.y, p = blockIdx.z;
    int wv = t >> 6, lane = t & 63, quad = lane >> 4, l15 = lane & 15;
    int ys = yt * 64 + wv * 16;
    const float* a2p = VmW + ((size_t)p * 512 + ys + l15) * 32 + quad * 8;
    float av[8];
    {
        float4 x0 = *(const float4*)a2p;
        float4 x1 = *(const float4*)(a2p + 4);
        av[0]=x0.x; av[1]=x0.y; av[2]=x0.z; av[3]=x0.w;
        av[4]=x1.x; av[5]=x1.y; av[6]=x1.z; av[7]=x1.w;
    }
    short8 A2h, A2l; split8(av, A2h, A2l);
    const short8* g1 = (const short8*)(GbF + (((yt * 4 + wv) * 64 + lane) << 4));
    short8 A1h = g1[0], A1l = g1[1];
    #pragma unroll
    for (int nt = 0; nt < 4; ++nt) {
        int wb = wt * 64 + nt * 16;
        const float* b1p = VmH + ((size_t)p * 512 + wb + l15) * 32 + quad * 8;
        float bv[8];
        float4 x0 = *(const float4*)b1p;
        float4 x1 = *(const float4*)(b1p + 4);
        bv[0]=x0.x; bv[1]=x0.y; bv[2]=x0.z; bv[3]=x0.w;
        bv[4]=x1.x; bv[5]=x1.y; bv[6]=x1.z; bv[7]=x1.w;
        short8 B1h, B1l; split8(bv, B1h, B1l);
        const short8* g2 = (const short8*)(GbF + (((wt * 4 + nt) * 64 + lane) << 4));
        short8 B2h = g2[0], B2l = g2[1];
        f32x4 acc = (f32x4){0.f,0.f,0.f,0.f};
        acc = MFMA16(A1h, B1h, acc);
        acc = MFMA16(A1l, B1h, acc);
        acc = MFMA16(A1h, B1l, acc);
        acc = MFMA16(A2h, B2h, acc);
        acc = MFMA16(A2l, B2h, acc);
        acc = MFMA16(A2h, B2l, acc);
        #pragma unroll
        for (int r = 0; r < 4; ++r)
            s[((size_t)p * 512 + ys + quad * 4 + r) * 512 + wb + l15] = bf16_rne(acc[r]);
    }
}

// ---------------------------------------------------------------------------
// MFMA FFN (R8 single-tile structure, grid 4096): h += gelu(W2.gelu(W1.s+b1)+b2).
// R9's 4-tile batching REGRESSED 2.5x (FETCH 49->268 MB): all-resident lockstep
// grid thrashed L2; dispatch-order streaming locality wins. Keep 1 tile/block.
// Only R9 idea retained: h-residual prefetch at kernel entry (registers),
// overlapping the tail h-read latency with staging+GEMMs.
// ---------------------------------------------------------------------------
union FfnSmem {
    unsigned int sB[64 * 33];   // 8448 B, staged bf16 s tile [pix][ch-pair]
    float oT[64 * 68];          // 17408 B, epilogue2 transpose tile
};

__global__ __launch_bounds__(256, 4) void k_ffn2m(const unsigned short* __restrict__ in, float* __restrict__ out,
                                                  const short* __restrict__ w1f, const float* __restrict__ b1v,
                                                  const short* __restrict__ w2f, const float* __restrict__ b2v) {
    __shared__ __align__(16) FfnSmem u;
    __shared__ __align__(16) unsigned int tT[64 * 64];
    int t = threadIdx.x;
    int pixBase = blockIdx.x * 64;
    int lane15 = t & 15;
    int quad   = (t >> 4) & 3;
    int wv     = t >> 6;
    int row    = wv * 16 + lane15;
    int pix0 = (t & 15) * 4;                   // RMW pixel base
    int c0 = (t >> 4) * 4;                     // RMW channel base

    // ---- issue independent loads up front: s tile + h residual prefetch ----
    float4 hres[4];
    #pragma unroll
    for (int i = 0; i < 4; ++i)
        hres[i] = *(const float4*)(out + (size_t)(c0 + i) * NPIX + pixBase + pix0);
    {
        int k  = t >> 3;                       // channel pair 0..31
        int po = t & 7;                        // pixel oct
        const uint4* r0 = (const uint4*)(in + (size_t)(2 * k) * NPIX + pixBase) + po;
        const uint4* r1 = (const uint4*)(in + (size_t)(2 * k + 1) * NPIX + pixBase) + po;
        uint4 a = *r0, b = *r1;
        unsigned int aw[4] = {a.x, a.y, a.z, a.w};
        unsigned int bw[4] = {b.x, b.y, b.z, b.w};
        #pragma unroll
        for (int i = 0; i < 4; ++i) {
            int pix = po * 8 + 2 * i;
            u.sB[pix * 33 + k]       = (aw[i] & 0xffffu) | (bw[i] << 16);
            u.sB[(pix + 1) * 33 + k] = (aw[i] >> 16) | (bw[i] & 0xffff0000u);
        }
    }

    short8 W1h[8], W1l[8];
    #pragma unroll
    for (int s8 = 0; s8 < 8; ++s8) {
        const short8* p = (const short8*)(w1f + (((size_t)s8 * 64 + (t & 63)) << 4));
        W1h[s8] = p[0]; W1l[s8] = p[1];
    }

    f32x4 acc[4];
    #pragma unroll
    for (int mt = 0; mt < 4; ++mt) acc[mt] = (f32x4){0.f, 0.f, 0.f, 0.f};

    __syncthreads();

    // ---- GEMM1: 2-term (s is bf16) ----
    #pragma unroll
    for (int kc = 0; kc < 2; ++kc) {
        union { unsigned int w[4]; short8 v; } bb;
        #pragma unroll
        for (int i = 0; i < 4; ++i)
            bb.w[i] = u.sB[row * 33 + kc * 16 + quad * 4 + i];
        #pragma unroll
        for (int mt = 0; mt < 4; ++mt) {
            int s8 = mt * 2 + kc;
            acc[mt] = MFMA16(W1h[s8], bb.v, acc[mt]);
            acc[mt] = MFMA16(W1l[s8], bb.v, acc[mt]);
        }
    }

    // ---- epilogue1: gelu, split, write tT ----
    #pragma unroll
    for (int mt = 0; mt < 4; ++mt) {
        const float* bp = b1v + mt * 16 + quad * 4;
        unsigned int pk[4];
        #pragma unroll
        for (int r = 0; r < 4; ++r) {
            float g = gelu_f(acc[mt][r] + bp[r]);
            pk[r] = bf16_split_pack(g);
        }
        int cg = mt * 4 + quad;
        unsigned int* dst = &tT[row * 64 + ((cg ^ lane15) << 2)];
        *(uint4*)dst = make_uint4(pk[0], pk[1], pk[2], pk[3]);
        acc[mt] = (f32x4){0.f, 0.f, 0.f, 0.f};
    }

    short8 W2h[8], W2l[8];
    #pragma unroll
    for (int s8 = 0; s8 < 8; ++s8) {
        const short8* p = (const short8*)(w2f + (((size_t)s8 * 64 + (t & 63)) << 4));
        W2h[s8] = p[0]; W2l[s8] = p[1];
    }

    __syncthreads();   // tT visible; also fences GEMM1 sB reads (oT may alias)

    // ---- GEMM2: 3-term (t stays split) ----
    #pragma unroll
    for (int kc = 0; kc < 2; ++kc) {
        int cg0 = kc * 8 + quad * 2;
        uint4 u0 = *(const uint4*)&tT[row * 64 + ((cg0 ^ lane15) << 2)];
        uint4 u1 = *(const uint4*)&tT[row * 64 + (((cg0 + 1) ^ lane15) << 2)];
        union { unsigned int w[4]; short8 v; } bh, bl;
        bh.w[0] = (u0.x & 0xffffu) | (u0.y << 16);
        bh.w[1] = (u0.z & 0xffffu) | (u0.w << 16);
        bh.w[2] = (u1.x & 0xffffu) | (u1.y << 16);
        bh.w[3] = (u1.z & 0xffffu) | (u1.w << 16);
        bl.w[0] = (u0.x >> 16) | (u0.y & 0xffff0000u);
        bl.w[1] = (u0.z >> 16) | (u0.w & 0xffff0000u);
        bl.w[2] = (u1.x >> 16) | (u1.y & 0xffff0000u);
        bl.w[3] = (u1.z >> 16) | (u1.w & 0xffff0000u);
        #pragma unroll
        for (int mt = 0; mt < 4; ++mt) {
            int s8 = mt * 2 + kc;
            acc[mt] = MFMA16(W2h[s8], bh.v, acc[mt]);
            acc[mt] = MFMA16(W2h[s8], bl.v, acc[mt]);
            acc[mt] = MFMA16(W2l[s8], bh.v, acc[mt]);
        }
    }

    // ---- epilogue2: gelu -> oT (aliases sB), then float4 h store w/ prefetched residual ----
    #pragma unroll
    for (int mt = 0; mt < 4; ++mt) {
        const float* bp = b2v + mt * 16 + quad * 4;
        #pragma unroll
        for (int r = 0; r < 4; ++r) {
            int o = mt * 16 + quad * 4 + r;
            u.oT[o * 68 + row] = gelu_f(acc[mt][r] + bp[r]);
        }
    }
    __syncthreads();
    #pragma unroll
    for (int i = 0; i < 4; ++i) {
        int c = c0 + i;
        float4 gv = *(const float4*)&u.oT[c * 68 + pix0];
        float4 cur = hres[i];
        cur.x += gv.x; cur.y += gv.y; cur.z += gv.z; cur.w += gv.w;
        *(float4*)(out + (size_t)c * NPIX + pixBase + pix0) = cur;
    }
}

// Decoder
__global__ __launch_bounds__(256) void k_dec(const float* __restrict__ h, const float* __restrict__ Wd,
                                             const float* __restrict__ bd, float* __restrict__ out) {
    int pix = blockIdx.x * 256 + threadIdx.x;
    float acc = bd[0];
    #pragma unroll 8
    for (int c = 0; c < 64; ++c) acc += Wd[c] * h[(size_t)c * NPIX + pix];
    out[pix] = acc;
}

extern "C" void kernel_launch(void* const* d_in, const int* in_sizes, int n_in,
                              void* d_out, int out_size, void* d_ws, size_t ws_size,
                              hipStream_t stream) {
    (void)in_sizes; (void)n_in; (void)out_size; (void)ws_size;
    const float* u   = (const float*)d_in[0];
    const float* xc  = (const float*)d_in[1];
    const float* We  = (const float*)d_in[2];
    const float* be  = (const float*)d_in[3];
    const float* W1  = (const float*)d_in[4];
    const float* b1  = (const float*)d_in[5];
    const float* W2  = (const float*)d_in[6];
    const float* b2  = (const float*)d_in[7];
    const float* Are = (const float*)d_in[8];
    const float* Aim = (const float*)d_in[9];
    const float* Wd  = (const float*)d_in[10];
    const float* bd  = (const float*)d_in[11];

    // workspace layout (float units), ~125 MB used
    float* ws  = (float*)d_ws;
    float* h   = ws;                            // 64 MB
    unsigned short* s = (unsigned short*)(h + (size_t)16777216);  // 32 MB (bf16), 64 MB slot
    float* VfH = (float*)((char*)s + (size_t)67108864); // 4 MB: [64][32][512]
    float* VfW = VfH + (size_t)1048576;         // 4 MB
    float* VmH = VfW + (size_t)1048576;         // 4 MB: [64][512][32]
    float* VmW = VmH + (size_t)1048576;         // 4 MB
    short* FbB = (short*)(VmW + 1048576);       // 64 KB
    short* GbF = FbB + 32768;                   // 64 KB
    short* Am  = GbF + 32768;                   // 6 MB: 65536 rec x 48 shorts
    short* Wpk = Am  + (size_t)65536 * 48;      // 128 KB

    k_setup<<<288, 256, 0, stream>>>(W1, W2, Are, Aim, FbB, GbF, Wpk, Am);
    k_enc<<<1024, 256, 0, stream>>>(u, xc, We, be, h);

    for (int l = 0; l < 4; ++l) {
        k_fwd<<<dim3(8, 64, 2), 256, 0, stream>>>(h, FbB, VfH, VfW);
        k_mix2<<<512, 256, 0, stream>>>(VfH, VfW, Am + (size_t)(l * 2) * ASLAB, VmH, VmW);
        k_inv<<<dim3(8, 8, 64), 256, 0, stream>>>(VmW, VmH, GbF, s);
        k_ffn2m<<<4096, 256, 0, stream>>>(s, h,
                                          Wpk + (size_t)(l * 2 + 0) * 8192, b1 + (size_t)l * 64,
                                          Wpk + (size_t)(l * 2 + 1) * 8192, b2 + (size_t)l * 64);
    }
    k_dec<<<1024, 256, 0, stream>>>(h, Wd, bd, (float*)d_out);
}

// Round 11
// 531.466 us; speedup vs baseline: 1.6617x; 1.0323x over previous
//
#include <hip/hip_runtime.h>

#define NPIX (512*512)

typedef __attribute__((ext_vector_type(8))) short short8;   // 8 bf16 in 4 VGPRs
typedef __attribute__((ext_vector_type(4))) float f32x4;    // MFMA accumulator

#define MFMA16(A, B, C) __builtin_amdgcn_mfma_f32_16x16x32_bf16((A), (B), (C), 0, 0, 0)

// JAX gelu(approximate=True): x * sigmoid(2*sqrt(2/pi)*(x+0.044715x^3)); inf-safe.
__device__ __forceinline__ float gelu_f(float x) {
    return x / (1.0f + __expf(-1.5957691216057308f * (x + 0.044715f * x * x * x)));
}

// f32 -> bf16 bits (RNE)
__device__ __forceinline__ unsigned short bf16_rne(float x) {
    unsigned int b = __float_as_uint(x);
    unsigned int r = b + 0x7fffu + ((b >> 16) & 1u);
    return (unsigned short)(r >> 16);
}
__device__ __forceinline__ float bf16_tof(unsigned short h) {
    return __uint_as_float(((unsigned int)h) << 16);
}
// split x ~= hi + lo (each bf16); dropped cross term in 3-term MFMA ~2^-18 rel.
__device__ __forceinline__ unsigned int bf16_split_pack(float x) {
    unsigned short hi = bf16_rne(x);
    unsigned short lo = bf16_rne(x - bf16_tof(hi));
    return (unsigned int)hi | ((unsigned int)lo << 16);
}
__device__ __forceinline__ void split8(const float* x, short8& h, short8& l) {
    #pragma unroll
    for (int j = 0; j < 8; ++j) {
        unsigned short hi = bf16_rne(x[j]);
        h[j] = (short)hi;
        l[j] = (short)bf16_rne(x[j] - bf16_tof(hi));
    }
}

#define ASLAB ((size_t)16 * 4 * 2 * 64 * 48)   // shorts per (l,ax) in Am

// ---------------------------------------------------------------------------
// Merged setup + encoder: blocks 0..15 basis tables, 16..31 FFN weights,
// 32..287 spectral A-weights, 288..1311 encoder. All independent; one launch.
// ---------------------------------------------------------------------------
__global__ __launch_bounds__(256) void k_setup(const float* __restrict__ W1, const float* __restrict__ W2,
                                               const float* __restrict__ Are, const float* __restrict__ Aim,
                                               const float* __restrict__ u, const float* __restrict__ xc,
                                               const float* __restrict__ We, const float* __restrict__ be,
                                               short* __restrict__ FbB, short* __restrict__ GbF,
                                               short* __restrict__ Wpk, short* __restrict__ Am,
                                               float* __restrict__ h) {
    int b = blockIdx.x;
    int t = threadIdx.x;
    if (b < 16) {
        // FbB: record (kc<16, nt<2, lane): elem j = Fb[kc*32+quad*8+j][nt*16+l15]
        // GbF: record (tt<32, lane): elem j = Gb[tt*16+l15][quad*8+j]
        int id = b * 256 + t;
        int lane = id & 63;
        int quad = lane >> 4, l15 = lane & 15;
        short* dst;
        int n0, nstep, o0, ostep;
        float wscale = 1.0f;
        if (id < 2048) {
            int nt = (id >> 6) & 1, kc = id >> 7;
            dst = FbB + id * 16;
            n0 = kc * 32 + quad * 8; nstep = 1;
            o0 = nt * 16 + l15;      ostep = 0;
        } else {
            int id2 = id - 2048;
            dst = GbF + id2 * 16;
            int tt = id2 >> 6;
            n0 = tt * 16 + l15;      nstep = 0;
            o0 = quad * 8;           ostep = 1;
            wscale = 1.0f / 512.0f;
        }
        #pragma unroll
        for (int j = 0; j < 8; ++j) {
            int n = n0 + nstep * j;
            int o = o0 + ostep * j;
            int m = o >> 1, ri = o & 1;
            int k = (n * m) & 511;
            float sv, cv;
            sincosf(6.283185307179586f * (1.0f / 512.0f) * (float)k, &sv, &cv);
            float v = ri ? -sv : cv;
            if (id >= 2048) v *= (m == 0 ? 1.0f : 2.0f) * wscale;
            unsigned short hi = bf16_rne(v);
            dst[j]     = (short)hi;
            dst[8 + j] = (short)bf16_rne(v - bf16_tof(hi));
        }
    } else if (b < 32) {
        int tid = (b - 16) * 256 + t;
        int lane = tid & 63;
        int kc = (tid >> 6) & 1;
        int mt = (tid >> 7) & 3;
        int wg = tid >> 9;
        int layer = wg >> 1, which = wg & 1;
        const float* Wsrc = (which ? W2 : W1) + (size_t)layer * 4096;
        int o  = mt * 16 + (lane & 15);
        int c0 = kc * 32 + ((lane >> 4) & 3) * 8;
        short* dst = Wpk + (size_t)tid * 16;
        #pragma unroll
        for (int j = 0; j < 8; ++j) {
            float x = Wsrc[o * 64 + c0 + j];
            unsigned short hi = bf16_rne(x);
            dst[j]     = (short)hi;
            dst[8 + j] = (short)bf16_rne(x - bf16_tof(hi));
        }
    } else if (b < 288) {
        // spectral A -> mix A-frag records of 48 shorts: [Ar_h8|Ar_l8|Ai_h8|Ai_l8|An_h8|An_l8]
        int id = (b - 32) * 256 + t;
        int lane = id & 63;
        int kc  = (id >> 6) & 1;
        int mt  = (id >> 7) & 3;
        int m   = (id >> 9) & 15;
        int lax = id >> 13;
        int l = lax >> 1, ax = lax & 1;
        int o  = mt * 16 + (lane & 15);
        int i0 = kc * 32 + ((lane >> 4) & 3) * 8;
        short* dst = Am + (size_t)id * 48;
        #pragma unroll
        for (int j = 0; j < 8; ++j) {
            size_t src = (((size_t)(l * 64 + o) * 64 + (i0 + j)) * 16 + m) * 2 + ax;
            float ar = Are[src], ai = Aim[src];
            unsigned short hh;
            hh = bf16_rne(ar);  dst[j]      = (short)hh; dst[8 + j]  = (short)bf16_rne(ar - bf16_tof(hh));
            hh = bf16_rne(ai);  dst[16 + j] = (short)hh; dst[24 + j] = (short)bf16_rne(ai - bf16_tof(hh));
            hh = bf16_rne(-ai); dst[32 + j] = (short)hh; dst[40 + j] = (short)bf16_rne(-ai - bf16_tof(hh));
        }
    } else {
        // encoder: h[p][pix] = We[p][0]*x0 + We[p][1]*x1 + We[p][2]*u + be[p]
        int pix = (b - 288) * 256 + t;
        float x0 = xc[pix], x1 = xc[NPIX + pix], uu = u[pix];
        #pragma unroll 8
        for (int p = 0; p < 64; ++p) {
            h[(size_t)p * NPIX + pix] = We[p * 3] * x0 + We[p * 3 + 1] * x1 + We[p * 3 + 2] * uu + be[p];
        }
    }
}

// ---------------------------------------------------------------------------
// Merged forward DFT, both axes, full K=512 per block:
//   axis 0 (H): VfH[p][o][w] = sum_y Fb[y][o]*h[p][y][w]   (B = h columns)
//   axis 1 (W): VfW[p][o][y] = sum_w Fb[w][o]*h[p][y][w]   (B = h rows)
// grid(8 ntile, 64 p, 2 axis), block 256; axis branch is block-uniform.
// ---------------------------------------------------------------------------
__global__ __launch_bounds__(256) void k_fwd(const float* __restrict__ h, const short* __restrict__ FbB,
                                             float* __restrict__ VfH, float* __restrict__ VfW) {
    int t = threadIdx.x;
    int ntb = blockIdx.x, p = blockIdx.y, axis = blockIdx.z;
    int wv = t >> 6, lane = t & 63, quad = lane >> 4, l15 = lane & 15;
    int n = ntb * 64 + wv * 16 + l15;
    f32x4 acc[2];
    acc[0] = (f32x4){0.f,0.f,0.f,0.f}; acc[1] = (f32x4){0.f,0.f,0.f,0.f};
    #pragma unroll 4
    for (int kc = 0; kc < 16; ++kc) {
        int kb = kc * 32 + quad * 8;
        float bv[8];
        if (axis == 0) {
            const float* hp = h + ((size_t)p * 512 + kb) * 512 + n;
            #pragma unroll
            for (int j = 0; j < 8; ++j) bv[j] = hp[(size_t)j * 512];
        } else {
            const float* hp = h + ((size_t)p * 512 + n) * 512 + kb;
            float4 x0 = *(const float4*)hp;
            float4 x1 = *(const float4*)(hp + 4);
            bv[0]=x0.x; bv[1]=x0.y; bv[2]=x0.z; bv[3]=x0.w;
            bv[4]=x1.x; bv[5]=x1.y; bv[6]=x1.z; bv[7]=x1.w;
        }
        short8 Bh, Bl; split8(bv, Bh, Bl);
        #pragma unroll
        for (int mt = 0; mt < 2; ++mt) {
            const short8* ap = (const short8*)(FbB + (((kc * 2 + mt) * 64 + lane) << 4));
            short8 Ah = ap[0], Al = ap[1];
            acc[mt] = MFMA16(Ah, Bh, acc[mt]);
            acc[mt] = MFMA16(Al, Bh, acc[mt]);
            acc[mt] = MFMA16(Ah, Bl, acc[mt]);
        }
    }
    float* vp = (axis ? VfW : VfH) + (size_t)p * 32 * 512;
    #pragma unroll
    for (int mt = 0; mt < 2; ++mt)
        #pragma unroll
        for (int r = 0; r < 4; ++r)
            vp[(size_t)(mt * 16 + quad * 4 + r) * 512 + n] = acc[mt][r];
}

// ---------------------------------------------------------------------------
// Merged mode mixing, both axes: D_re = Ar.Br + An.Bi, D_im = Ar.Bi + Ai.Br.
// grid 512 (axis = bid>>8; m = bid&15, otile = (bid>>4)&15), block 256.
// ---------------------------------------------------------------------------
__global__ __launch_bounds__(256) void k_mix2(const float* __restrict__ VfH, const float* __restrict__ VfW,
                                              const short* __restrict__ AmL,
                                              float* __restrict__ VmH, float* __restrict__ VmW) {
    __shared__ unsigned int BT[2 * 64 * 33];
    int bid = blockIdx.x;
    int axis = bid >> 8;
    int m  = bid & 15;
    int ot = (bid >> 4) & 15;
    const float* Vf = axis ? VfW : VfH;
    float* Vm = axis ? VmW : VmH;
    const short* Am = AmL + (size_t)axis * ASLAB;
    int t = threadIdx.x;
    #pragma unroll
    for (int it = 0; it < 16; ++it) {
        int idx = it * 256 + t;
        int oth = idx & 31, ri = (idx >> 5) & 1, i = idx >> 6;
        float v = Vf[((size_t)i * 32 + m * 2 + ri) * 512 + ot * 32 + oth];
        BT[(ri * 64 + i) * 33 + oth] = bf16_split_pack(v);
    }
    __syncthreads();
    int wv = t >> 6, lane = t & 63, quad = lane >> 4, l15 = lane & 15;
    int nt = wv & 1, mtp = wv >> 1;
    f32x4 aR[2], aI[2];
    aR[0]=(f32x4){0.f,0.f,0.f,0.f}; aR[1]=aR[0]; aI[0]=aR[0]; aI[1]=aR[0];
    #pragma unroll
    for (int kc = 0; kc < 2; ++kc) {
        short8 Brh, Brl, Bih, Bil;
        #pragma unroll
        for (int j = 0; j < 8; ++j) {
            int i = kc * 32 + quad * 8 + j;
            unsigned int br = BT[i * 33 + nt * 16 + l15];
            unsigned int bi = BT[(64 + i) * 33 + nt * 16 + l15];
            Brh[j] = (short)(br & 0xffffu); Brl[j] = (short)(br >> 16);
            Bih[j] = (short)(bi & 0xffffu); Bil[j] = (short)(bi >> 16);
        }
        #pragma unroll
        for (int mi = 0; mi < 2; ++mi) {
            int mt = mtp * 2 + mi;
            const short8* ap = (const short8*)(Am + ((size_t)(((m * 4 + mt) * 2 + kc) * 64 + lane)) * 48);
            short8 Arh = ap[0], Arl = ap[1], Aih = ap[2], Ail = ap[3], Anh = ap[4], Anl = ap[5];
            aR[mi] = MFMA16(Arh, Brh, aR[mi]);
            aR[mi] = MFMA16(Arl, Brh, aR[mi]);
            aR[mi] = MFMA16(Arh, Brl, aR[mi]);
            aR[mi] = MFMA16(Anh, Bih, aR[mi]);
            aR[mi] = MFMA16(Anl, Bih, aR[mi]);
            aR[mi] = MFMA16(Anh, Bil, aR[mi]);
            aI[mi] = MFMA16(Arh, Bih, aI[mi]);
            aI[mi] = MFMA16(Arl, Bih, aI[mi]);
            aI[mi] = MFMA16(Arh, Bil, aI[mi]);
            aI[mi] = MFMA16(Aih, Brh, aI[mi]);
            aI[mi] = MFMA16(Ail, Brh, aI[mi]);
            aI[mi] = MFMA16(Aih, Brl, aI[mi]);
        }
    }
    int oth = ot * 32 + nt * 16 + l15;
    #pragma unroll
    for (int mi = 0; mi < 2; ++mi) {
        int o = (mtp * 2 + mi) * 16 + quad * 4;
        #pragma unroll
        for (int r = 0; r < 4; ++r) {
            float2 v; v.x = aR[mi][r]; v.y = aI[mi][r];
            *(float2*)(Vm + ((size_t)(o + r) * 512 + oth) * 32 + m * 2) = v;
        }
    }
}

// ---------------------------------------------------------------------------
// Fused inverse DFT (both axes) -> s as PLAIN BF16 (2 B).
// grid(8 wt, 8 yt, 64 p), block 256.
// ---------------------------------------------------------------------------
__global__ __launch_bounds__(256) void k_inv(const float* __restrict__ VmW, const float* __restrict__ VmH,
                                             const short* __restrict__ GbF, unsigned short* __restrict__ s) {
    int t = threadIdx.x;
    int wt = blockIdx.x, yt = blockIdx.y, p = blockIdx.z;
    int wv = t >> 6, lane = t & 63, quad = lane >> 4, l15 = lane & 15;
    int ys = yt * 64 + wv * 16;
    const float* a2p = VmW + ((size_t)p * 512 + ys + l15) * 32 + quad * 8;
    float av[8];
    {
        float4 x0 = *(const float4*)a2p;
        float4 x1 = *(const float4*)(a2p + 4);
        av[0]=x0.x; av[1]=x0.y; av[2]=x0.z; av[3]=x0.w;
        av[4]=x1.x; av[5]=x1.y; av[6]=x1.z; av[7]=x1.w;
    }
    short8 A2h, A2l; split8(av, A2h, A2l);
    const short8* g1 = (const short8*)(GbF + (((yt * 4 + wv) * 64 + lane) << 4));
    short8 A1h = g1[0], A1l = g1[1];
    #pragma unroll
    for (int nt = 0; nt < 4; ++nt) {
        int wb = wt * 64 + nt * 16;
        const float* b1p = VmH + ((size_t)p * 512 + wb + l15) * 32 + quad * 8;
        float bv[8];
        float4 x0 = *(const float4*)b1p;
        float4 x1 = *(const float4*)(b1p + 4);
        bv[0]=x0.x; bv[1]=x0.y; bv[2]=x0.z; bv[3]=x0.w;
        bv[4]=x1.x; bv[5]=x1.y; bv[6]=x1.z; bv[7]=x1.w;
        short8 B1h, B1l; split8(bv, B1h, B1l);
        const short8* g2 = (const short8*)(GbF + (((wt * 4 + nt) * 64 + lane) << 4));
        short8 B2h = g2[0], B2l = g2[1];
        f32x4 acc = (f32x4){0.f,0.f,0.f,0.f};
        acc = MFMA16(A1h, B1h, acc);
        acc = MFMA16(A1l, B1h, acc);
        acc = MFMA16(A1h, B1l, acc);
        acc = MFMA16(A2h, B2h, acc);
        acc = MFMA16(A2l, B2h, acc);
        acc = MFMA16(A2h, B2l, acc);
        #pragma unroll
        for (int r = 0; r < 4; ++r)
            s[((size_t)p * 512 + ys + quad * 4 + r) * 512 + wb + l15] = bf16_rne(acc[r]);
    }
}

// ---------------------------------------------------------------------------
// MFMA FFN (single-tile, grid 4096): h += gelu(W2.gelu(W1.s+b1)+b2).
// last==1 (layer 3): skip the h store; instead fuse the decoder — per-thread
// partials Wd[c].h_new over its 4 ch x 4 pix, reduced across the 16 ch-groups
// via stride-65 LDS aliasing dead tT, written straight to d_out. Saves the
// k_dec launch + 64 MB h write.
// ---------------------------------------------------------------------------
union FfnSmem {
    unsigned int sB[64 * 33];   // 8448 B, staged bf16 s tile [pix][ch-pair]
    float oT[64 * 68];          // 17408 B, epilogue2 transpose tile
};

__global__ __launch_bounds__(256, 4) void k_ffn2m(const unsigned short* __restrict__ in, float* __restrict__ out,
                                                  const short* __restrict__ w1f, const float* __restrict__ b1v,
                                                  const short* __restrict__ w2f, const float* __restrict__ b2v,
                                                  const float* __restrict__ Wd, const float* __restrict__ bd,
                                                  float* __restrict__ dout, int last) {
    __shared__ __align__(16) FfnSmem u;
    __shared__ __align__(16) unsigned int tT[64 * 64];
    int t = threadIdx.x;
    int pixBase = blockIdx.x * 64;
    int lane15 = t & 15;
    int quad   = (t >> 4) & 3;
    int wv     = t >> 6;
    int row    = wv * 16 + lane15;
    int pix0 = (t & 15) * 4;                   // RMW pixel base
    int c0 = (t >> 4) * 4;                     // RMW channel base

    // ---- issue independent loads up front: h residual prefetch + s tile ----
    float4 hres[4];
    #pragma unroll
    for (int i = 0; i < 4; ++i)
        hres[i] = *(const float4*)(out + (size_t)(c0 + i) * NPIX + pixBase + pix0);
    {
        int k  = t >> 3;                       // channel pair 0..31
        int po = t & 7;                        // pixel oct
        const uint4* r0 = (const uint4*)(in + (size_t)(2 * k) * NPIX + pixBase) + po;
        const uint4* r1 = (const uint4*)(in + (size_t)(2 * k + 1) * NPIX + pixBase) + po;
        uint4 a = *r0, b = *r1;
        unsigned int aw[4] = {a.x, a.y, a.z, a.w};
        unsigned int bw[4] = {b.x, b.y, b.z, b.w};
        #pragma unroll
        for (int i = 0; i < 4; ++i) {
            int pix = po * 8 + 2 * i;
            u.sB[pix * 33 + k]       = (aw[i] & 0xffffu) | (bw[i] << 16);
            u.sB[(pix + 1) * 33 + k] = (aw[i] >> 16) | (bw[i] & 0xffff0000u);
        }
    }

    short8 W1h[8], W1l[8];
    #pragma unroll
    for (int s8 = 0; s8 < 8; ++s8) {
        const short8* p = (const short8*)(w1f + (((size_t)s8 * 64 + (t & 63)) << 4));
        W1h[s8] = p[0]; W1l[s8] = p[1];
    }

    f32x4 acc[4];
    #pragma unroll
    for (int mt = 0; mt < 4; ++mt) acc[mt] = (f32x4){0.f, 0.f, 0.f, 0.f};

    __syncthreads();

    // ---- GEMM1: 2-term (s is bf16) ----
    #pragma unroll
    for (int kc = 0; kc < 2; ++kc) {
        union { unsigned int w[4]; short8 v; } bb;
        #pragma unroll
        for (int i = 0; i < 4; ++i)
            bb.w[i] = u.sB[row * 33 + kc * 16 + quad * 4 + i];
        #pragma unroll
        for (int mt = 0; mt < 4; ++mt) {
            int s8 = mt * 2 + kc;
            acc[mt] = MFMA16(W1h[s8], bb.v, acc[mt]);
            acc[mt] = MFMA16(W1l[s8], bb.v, acc[mt]);
        }
    }

    // ---- epilogue1: gelu, split, write tT ----
    #pragma unroll
    for (int mt = 0; mt < 4; ++mt) {
        const float* bp = b1v + mt * 16 + quad * 4;
        unsigned int pk[4];
        #pragma unroll
        for (int r = 0; r < 4; ++r) {
            float g = gelu_f(acc[mt][r] + bp[r]);
            pk[r] = bf16_split_pack(g);
        }
        int cg = mt * 4 + quad;
        unsigned int* dst = &tT[row * 64 + ((cg ^ lane15) << 2)];
        *(uint4*)dst = make_uint4(pk[0], pk[1], pk[2], pk[3]);
        acc[mt] = (f32x4){0.f, 0.f, 0.f, 0.f};
    }

    short8 W2h[8], W2l[8];
    #pragma unroll
    for (int s8 = 0; s8 < 8; ++s8) {
        const short8* p = (const short8*)(w2f + (((size_t)s8 * 64 + (t & 63)) << 4));
        W2h[s8] = p[0]; W2l[s8] = p[1];
    }

    __syncthreads();   // tT visible; also fences GEMM1 sB reads (oT may alias)

    // ---- GEMM2: 3-term (t stays split) ----
    #pragma unroll
    for (int kc = 0; kc < 2; ++kc) {
        int cg0 = kc * 8 + quad * 2;
        uint4 u0 = *(const uint4*)&tT[row * 64 + ((cg0 ^ lane15) << 2)];
        uint4 u1 = *(const uint4*)&tT[row * 64 + (((cg0 + 1) ^ lane15) << 2)];
        union { unsigned int w[4]; short8 v; } bh, bl;
        bh.w[0] = (u0.x & 0xffffu) | (u0.y << 16);
        bh.w[1] = (u0.z & 0xffffu) | (u0.w << 16);
        bh.w[2] = (u1.x & 0xffffu) | (u1.y << 16);
        bh.w[3] = (u1.z & 0xffffu) | (u1.w << 16);
        bl.w[0] = (u0.x >> 16) | (u0.y & 0xffff0000u);
        bl.w[1] = (u0.z >> 16) | (u0.w & 0xffff0000u);
        bl.w[2] = (u1.x >> 16) | (u1.y & 0xffff0000u);
        bl.w[3] = (u1.z >> 16) | (u1.w & 0xffff0000u);
        #pragma unroll
        for (int mt = 0; mt < 4; ++mt) {
            int s8 = mt * 2 + kc;
            acc[mt] = MFMA16(W2h[s8], bh.v, acc[mt]);
            acc[mt] = MFMA16(W2h[s8], bl.v, acc[mt]);
            acc[mt] = MFMA16(W2l[s8], bh.v, acc[mt]);
        }
    }

    // ---- epilogue2: gelu -> oT (aliases sB) ----
    #pragma unroll
    for (int mt = 0; mt < 4; ++mt) {
        const float* bp = b2v + mt * 16 + quad * 4;
        #pragma unroll
        for (int r = 0; r < 4; ++r) {
            int o = mt * 16 + quad * 4 + r;
            u.oT[o * 68 + row] = gelu_f(acc[mt][r] + bp[r]);
        }
    }
    __syncthreads();

    if (!last) {
        // ---- h += increment (float4, prefetched residual) ----
        #pragma unroll
        for (int i = 0; i < 4; ++i) {
            int c = c0 + i;
            float4 gv = *(const float4*)&u.oT[c * 68 + pix0];
            float4 cur = hres[i];
            cur.x += gv.x; cur.y += gv.y; cur.z += gv.z; cur.w += gv.w;
            *(float4*)(out + (size_t)c * NPIX + pixBase + pix0) = cur;
        }
    } else {
        // ---- fused decoder: dout[pix] = sum_c Wd[c]*(hres+gv) + bd; skip h store ----
        float* red = (float*)tT;               // stride 65: write 2-way, read 2-way (free)
        float part[4] = {0.f, 0.f, 0.f, 0.f};
        #pragma unroll
        for (int i = 0; i < 4; ++i) {
            int c = c0 + i;
            float wd = Wd[c];
            float4 gv = *(const float4*)&u.oT[c * 68 + pix0];
            float4 cur = hres[i];
            part[0] += wd * (cur.x + gv.x);
            part[1] += wd * (cur.y + gv.y);
            part[2] += wd * (cur.z + gv.z);
            part[3] += wd * (cur.w + gv.w);
        }
        int g = t >> 4;                        // channel group 0..15
        #pragma unroll
        for (int j = 0; j < 4; ++j)
            red[g * 65 + pix0 + j] = part[j];
        __syncthreads();
        if (t < 64) {
            float sum = bd[0];
            #pragma unroll
            for (int gg = 0; gg < 16; ++gg)
                sum += red[gg * 65 + t];
            dout[pixBase + t] = sum;
        }
    }
}

extern "C" void kernel_launch(void* const* d_in, const int* in_sizes, int n_in,
                              void* d_out, int out_size, void* d_ws, size_t ws_size,
                              hipStream_t stream) {
    (void)in_sizes; (void)n_in; (void)out_size; (void)ws_size;
    const float* u   = (const float*)d_in[0];
    const float* xc  = (const float*)d_in[1];
    const float* We  = (const float*)d_in[2];
    const float* be  = (const float*)d_in[3];
    const float* W1  = (const float*)d_in[4];
    const float* b1  = (const float*)d_in[5];
    const float* W2  = (const float*)d_in[6];
    const float* b2  = (const float*)d_in[7];
    const float* Are = (const float*)d_in[8];
    const float* Aim = (const float*)d_in[9];
    const float* Wd  = (const float*)d_in[10];
    const float* bd  = (const float*)d_in[11];

    // workspace layout (float units), ~125 MB used
    float* ws  = (float*)d_ws;
    float* h   = ws;                            // 64 MB
    unsigned short* s = (unsigned short*)(h + (size_t)16777216);  // 32 MB (bf16), 64 MB slot
    float* VfH = (float*)((char*)s + (size_t)67108864); // 4 MB: [64][32][512]
    float* VfW = VfH + (size_t)1048576;         // 4 MB
    float* VmH = VfW + (size_t)1048576;         // 4 MB: [64][512][32]
    float* VmW = VmH + (size_t)1048576;         // 4 MB
    short* FbB = (short*)(VmW + 1048576);       // 64 KB
    short* GbF = FbB + 32768;                   // 64 KB
    short* Am  = GbF + 32768;                   // 6 MB: 65536 rec x 48 shorts
    short* Wpk = Am  + (size_t)65536 * 48;      // 128 KB

    k_setup<<<1312, 256, 0, stream>>>(W1, W2, Are, Aim, u, xc, We, be,
                                      FbB, GbF, Wpk, Am, h);

    for (int l = 0; l < 4; ++l) {
        k_fwd<<<dim3(8, 64, 2), 256, 0, stream>>>(h, FbB, VfH, VfW);
        k_mix2<<<512, 256, 0, stream>>>(VfH, VfW, Am + (size_t)(l * 2) * ASLAB, VmH, VmW);
        k_inv<<<dim3(8, 8, 64), 256, 0, stream>>>(VmW, VmH, GbF, s);
        k_ffn2m<<<4096, 256, 0, stream>>>(s, h,
                                          Wpk + (size_t)(l * 2 + 0) * 8192, b1 + (size_t)l * 64,
                                          Wpk + (size_t)(l * 2 + 1) * 8192, b2 + (size_t)l * 64,
                                          Wd, bd, (float*)d_out, (l == 3) ? 1 : 0);
    }
}

// Round 12
// 525.136 us; speedup vs baseline: 1.6818x; 1.0121x over previous
//
#include <hip/hip_runtime.h>

#define NPIX (512*512)

typedef __attribute__((ext_vector_type(8))) short short8;   // 8 bf16 in 4 VGPRs
typedef __attribute__((ext_vector_type(4))) float f32x4;    // MFMA accumulator

#define MFMA16(A, B, C) __builtin_amdgcn_mfma_f32_16x16x32_bf16((A), (B), (C), 0, 0, 0)

// JAX gelu(approximate=True): x * sigmoid(2*sqrt(2/pi)*(x+0.044715x^3)); inf-safe.
__device__ __forceinline__ float gelu_f(float x) {
    return x / (1.0f + __expf(-1.5957691216057308f * (x + 0.044715f * x * x * x)));
}

// f32 -> bf16 bits (RNE)
__device__ __forceinline__ unsigned short bf16_rne(float x) {
    unsigned int b = __float_as_uint(x);
    unsigned int r = b + 0x7fffu + ((b >> 16) & 1u);
    return (unsigned short)(r >> 16);
}
__device__ __forceinline__ float bf16_tof(unsigned short h) {
    return __uint_as_float(((unsigned int)h) << 16);
}
__device__ __forceinline__ unsigned int bf16_split_pack(float x) {
    unsigned short hi = bf16_rne(x);
    unsigned short lo = bf16_rne(x - bf16_tof(hi));
    return (unsigned int)hi | ((unsigned int)lo << 16);
}
__device__ __forceinline__ void split8(const float* x, short8& h, short8& l) {
    #pragma unroll
    for (int j = 0; j < 8; ++j) {
        unsigned short hi = bf16_rne(x[j]);
        h[j] = (short)hi;
        l[j] = (short)bf16_rne(x[j] - bf16_tof(hi));
    }
}

#define ASLAB ((size_t)16 * 4 * 2 * 64 * 48)   // shorts per (l,ax) in Am

// ---------------------------------------------------------------------------
// Merged setup + encoder: blocks 0..15 basis tables, 16..31 FFN weights,
// 32..287 spectral A-weights, 288..1311 encoder (h stored bf16).
// ---------------------------------------------------------------------------
__global__ __launch_bounds__(256) void k_setup(const float* __restrict__ W1, const float* __restrict__ W2,
                                               const float* __restrict__ Are, const float* __restrict__ Aim,
                                               const float* __restrict__ u, const float* __restrict__ xc,
                                               const float* __restrict__ We, const float* __restrict__ be,
                                               short* __restrict__ FbB, short* __restrict__ GbF,
                                               short* __restrict__ Wpk, short* __restrict__ Am,
                                               unsigned short* __restrict__ h) {
    int b = blockIdx.x;
    int t = threadIdx.x;
    if (b < 16) {
        int id = b * 256 + t;
        int lane = id & 63;
        int quad = lane >> 4, l15 = lane & 15;
        short* dst;
        int n0, nstep, o0, ostep;
        float wscale = 1.0f;
        if (id < 2048) {
            int nt = (id >> 6) & 1, kc = id >> 7;
            dst = FbB + id * 16;
            n0 = kc * 32 + quad * 8; nstep = 1;
            o0 = nt * 16 + l15;      ostep = 0;
        } else {
            int id2 = id - 2048;
            dst = GbF + id2 * 16;
            int tt = id2 >> 6;
            n0 = tt * 16 + l15;      nstep = 0;
            o0 = quad * 8;           ostep = 1;
            wscale = 1.0f / 512.0f;
        }
        #pragma unroll
        for (int j = 0; j < 8; ++j) {
            int n = n0 + nstep * j;
            int o = o0 + ostep * j;
            int m = o >> 1, ri = o & 1;
            int k = (n * m) & 511;
            float sv, cv;
            sincosf(6.283185307179586f * (1.0f / 512.0f) * (float)k, &sv, &cv);
            float v = ri ? -sv : cv;
            if (id >= 2048) v *= (m == 0 ? 1.0f : 2.0f) * wscale;
            unsigned short hi = bf16_rne(v);
            dst[j]     = (short)hi;
            dst[8 + j] = (short)bf16_rne(v - bf16_tof(hi));
        }
    } else if (b < 32) {
        int tid = (b - 16) * 256 + t;
        int lane = tid & 63;
        int kc = (tid >> 6) & 1;
        int mt = (tid >> 7) & 3;
        int wg = tid >> 9;
        int layer = wg >> 1, which = wg & 1;
        const float* Wsrc = (which ? W2 : W1) + (size_t)layer * 4096;
        int o  = mt * 16 + (lane & 15);
        int c0 = kc * 32 + ((lane >> 4) & 3) * 8;
        short* dst = Wpk + (size_t)tid * 16;
        #pragma unroll
        for (int j = 0; j < 8; ++j) {
            float x = Wsrc[o * 64 + c0 + j];
            unsigned short hi = bf16_rne(x);
            dst[j]     = (short)hi;
            dst[8 + j] = (short)bf16_rne(x - bf16_tof(hi));
        }
    } else if (b < 288) {
        int id = (b - 32) * 256 + t;
        int lane = id & 63;
        int kc  = (id >> 6) & 1;
        int mt  = (id >> 7) & 3;
        int m   = (id >> 9) & 15;
        int lax = id >> 13;
        int l = lax >> 1, ax = lax & 1;
        int o  = mt * 16 + (lane & 15);
        int i0 = kc * 32 + ((lane >> 4) & 3) * 8;
        short* dst = Am + (size_t)id * 48;
        #pragma unroll
        for (int j = 0; j < 8; ++j) {
            size_t src = (((size_t)(l * 64 + o) * 64 + (i0 + j)) * 16 + m) * 2 + ax;
            float ar = Are[src], ai = Aim[src];
            unsigned short hh;
            hh = bf16_rne(ar);  dst[j]      = (short)hh; dst[8 + j]  = (short)bf16_rne(ar - bf16_tof(hh));
            hh = bf16_rne(ai);  dst[16 + j] = (short)hh; dst[24 + j] = (short)bf16_rne(ai - bf16_tof(hh));
            hh = bf16_rne(-ai); dst[32 + j] = (short)hh; dst[40 + j] = (short)bf16_rne(-ai - bf16_tof(hh));
        }
    } else {
        // encoder: h[p][pix] = bf16(We.x + be)
        int pix = (b - 288) * 256 + t;
        float x0 = xc[pix], x1 = xc[NPIX + pix], uu = u[pix];
        #pragma unroll 8
        for (int p = 0; p < 64; ++p) {
            float v = We[p * 3] * x0 + We[p * 3 + 1] * x1 + We[p * 3 + 2] * uu + be[p];
            h[(size_t)p * NPIX + pix] = bf16_rne(v);
        }
    }
}

// ---------------------------------------------------------------------------
// Merged forward DFT, both axes, h in bf16 (B-frag is a direct reinterpret;
// A-side basis stays split for exact twiddles -> 2-term MFMA):
//   axis 0 (H): VfH[p][o][w] = sum_y Fb[y][o]*h[p][y][w]   (column u16 loads)
//   axis 1 (W): VfW[p][o][y] = sum_w Fb[w][o]*h[p][y][w]   (row short8 loads)
// grid(8 ntile, 64 p, 2 axis), block 256.
// ---------------------------------------------------------------------------
__global__ __launch_bounds__(256) void k_fwd(const unsigned short* __restrict__ h, const short* __restrict__ FbB,
                                             float* __restrict__ VfH, float* __restrict__ VfW) {
    int t = threadIdx.x;
    int ntb = blockIdx.x, p = blockIdx.y, axis = blockIdx.z;
    int wv = t >> 6, lane = t & 63, quad = lane >> 4, l15 = lane & 15;
    int n = ntb * 64 + wv * 16 + l15;
    f32x4 acc[2];
    acc[0] = (f32x4){0.f,0.f,0.f,0.f}; acc[1] = (f32x4){0.f,0.f,0.f,0.f};
    #pragma unroll 4
    for (int kc = 0; kc < 16; ++kc) {
        int kb = kc * 32 + quad * 8;
        short8 Bv;
        if (axis == 0) {
            const unsigned short* hp = h + ((size_t)p * 512 + kb) * 512 + n;
            #pragma unroll
            for (int j = 0; j < 8; ++j) Bv[j] = (short)hp[(size_t)j * 512];
        } else {
            const unsigned short* hp = h + ((size_t)p * 512 + n) * 512 + kb;
            Bv = *(const short8*)hp;
        }
        #pragma unroll
        for (int mt = 0; mt < 2; ++mt) {
            const short8* ap = (const short8*)(FbB + (((kc * 2 + mt) * 64 + lane) << 4));
            short8 Ah = ap[0], Al = ap[1];
            acc[mt] = MFMA16(Ah, Bv, acc[mt]);
            acc[mt] = MFMA16(Al, Bv, acc[mt]);
        }
    }
    float* vp = (axis ? VfW : VfH) + (size_t)p * 32 * 512;
    #pragma unroll
    for (int mt = 0; mt < 2; ++mt)
        #pragma unroll
        for (int r = 0; r < 4; ++r)
            vp[(size_t)(mt * 16 + quad * 4 + r) * 512 + n] = acc[mt][r];
}

// ---------------------------------------------------------------------------
// Merged mode mixing, both axes: D_re = Ar.Br + An.Bi, D_im = Ar.Bi + Ai.Br.
// grid 512 (axis = bid>>8; m = bid&15, otile = (bid>>4)&15), block 256.
// ---------------------------------------------------------------------------
__global__ __launch_bounds__(256) void k_mix2(const float* __restrict__ VfH, const float* __restrict__ VfW,
                                              const short* __restrict__ AmL,
                                              float* __restrict__ VmH, float* __restrict__ VmW) {
    __shared__ unsigned int BT[2 * 64 * 33];
    int bid = blockIdx.x;
    int axis = bid >> 8;
    int m  = bid & 15;
    int ot = (bid >> 4) & 15;
    const float* Vf = axis ? VfW : VfH;
    float* Vm = axis ? VmW : VmH;
    const short* Am = AmL + (size_t)axis * ASLAB;
    int t = threadIdx.x;
    #pragma unroll
    for (int it = 0; it < 16; ++it) {
        int idx = it * 256 + t;
        int oth = idx & 31, ri = (idx >> 5) & 1, i = idx >> 6;
        float v = Vf[((size_t)i * 32 + m * 2 + ri) * 512 + ot * 32 + oth];
        BT[(ri * 64 + i) * 33 + oth] = bf16_split_pack(v);
    }
    __syncthreads();
    int wv = t >> 6, lane = t & 63, quad = lane >> 4, l15 = lane & 15;
    int nt = wv & 1, mtp = wv >> 1;
    f32x4 aR[2], aI[2];
    aR[0]=(f32x4){0.f,0.f,0.f,0.f}; aR[1]=aR[0]; aI[0]=aR[0]; aI[1]=aR[0];
    #pragma unroll
    for (int kc = 0; kc < 2; ++kc) {
        short8 Brh, Brl, Bih, Bil;
        #pragma unroll
        for (int j = 0; j < 8; ++j) {
            int i = kc * 32 + quad * 8 + j;
            unsigned int br = BT[i * 33 + nt * 16 + l15];
            unsigned int bi = BT[(64 + i) * 33 + nt * 16 + l15];
            Brh[j] = (short)(br & 0xffffu); Brl[j] = (short)(br >> 16);
            Bih[j] = (short)(bi & 0xffffu); Bil[j] = (short)(bi >> 16);
        }
        #pragma unroll
        for (int mi = 0; mi < 2; ++mi) {
            int mt = mtp * 2 + mi;
            const short8* ap = (const short8*)(Am + ((size_t)(((m * 4 + mt) * 2 + kc) * 64 + lane)) * 48);
            short8 Arh = ap[0], Arl = ap[1], Aih = ap[2], Ail = ap[3], Anh = ap[4], Anl = ap[5];
            aR[mi] = MFMA16(Arh, Brh, aR[mi]);
            aR[mi] = MFMA16(Arl, Brh, aR[mi]);
            aR[mi] = MFMA16(Arh, Brl, aR[mi]);
            aR[mi] = MFMA16(Anh, Bih, aR[mi]);
            aR[mi] = MFMA16(Anl, Bih, aR[mi]);
            aR[mi] = MFMA16(Anh, Bil, aR[mi]);
            aI[mi] = MFMA16(Arh, Bih, aI[mi]);
            aI[mi] = MFMA16(Arl, Bih, aI[mi]);
            aI[mi] = MFMA16(Arh, Bil, aI[mi]);
            aI[mi] = MFMA16(Aih, Brh, aI[mi]);
            aI[mi] = MFMA16(Ail, Brh, aI[mi]);
            aI[mi] = MFMA16(Aih, Brl, aI[mi]);
        }
    }
    int oth = ot * 32 + nt * 16 + l15;
    #pragma unroll
    for (int mi = 0; mi < 2; ++mi) {
        int o = (mtp * 2 + mi) * 16 + quad * 4;
        #pragma unroll
        for (int r = 0; r < 4; ++r) {
            float2 v; v.x = aR[mi][r]; v.y = aI[mi][r];
            *(float2*)(Vm + ((size_t)(o + r) * 512 + oth) * 32 + m * 2) = v;
        }
    }
}

// ---------------------------------------------------------------------------
// Fused inverse DFT (both axes) -> s as PLAIN BF16 (2 B).
// grid(8 wt, 8 yt, 64 p), block 256.
// ---------------------------------------------------------------------------
__global__ __launch_bounds__(256) void k_inv(const float* __restrict__ VmW, const float* __restrict__ VmH,
                                             const short* __restrict__ GbF, unsigned short* __restrict__ s) {
    int t = threadIdx.x;
    int wt = blockIdx.x, yt = blockIdx.y, p = blockIdx.z;
    int wv = t >> 6, lane = t & 63, quad = lane >> 4, l15 = lane & 15;
    int ys = yt * 64 + wv * 16;
    const float* a2p = VmW + ((size_t)p * 512 + ys + l15) * 32 + quad * 8;
    float av[8];
    {
        float4 x0 = *(const float4*)a2p;
        float4 x1 = *(const float4*)(a2p + 4);
        av[0]=x0.x; av[1]=x0.y; av[2]=x0.z; av[3]=x0.w;
        av[4]=x1.x; av[5]=x1.y; av[6]=x1.z; av[7]=x1.w;
    }
    short8 A2h, A2l; split8(av, A2h, A2l);
    const short8* g1 = (const short8*)(GbF + (((yt * 4 + wv) * 64 + lane) << 4));
    short8 A1h = g1[0], A1l = g1[1];
    #pragma unroll
    for (int nt = 0; nt < 4; ++nt) {
        int wb = wt * 64 + nt * 16;
        const float* b1p = VmH + ((size_t)p * 512 + wb + l15) * 32 + quad * 8;
        float bv[8];
        float4 x0 = *(const float4*)b1p;
        float4 x1 = *(const float4*)(b1p + 4);
        bv[0]=x0.x; bv[1]=x0.y; bv[2]=x0.z; bv[3]=x0.w;
        bv[4]=x1.x; bv[5]=x1.y; bv[6]=x1.z; bv[7]=x1.w;
        short8 B1h, B1l; split8(bv, B1h, B1l);
        const short8* g2 = (const short8*)(GbF + (((wt * 4 + nt) * 64 + lane) << 4));
        short8 B2h = g2[0], B2l = g2[1];
        f32x4 acc = (f32x4){0.f,0.f,0.f,0.f};
        acc = MFMA16(A1h, B1h, acc);
        acc = MFMA16(A1l, B1h, acc);
        acc = MFMA16(A1h, B1l, acc);
        acc = MFMA16(A2h, B2h, acc);
        acc = MFMA16(A2l, B2h, acc);
        acc = MFMA16(A2h, B2l, acc);
        #pragma unroll
        for (int r = 0; r < 4; ++r)
            s[((size_t)p * 512 + ys + quad * 4 + r) * 512 + wb + l15] = bf16_rne(acc[r]);
    }
}

// ---------------------------------------------------------------------------
// MFMA FFN (single-tile, grid 4096): h(bf16) += gelu(W2.gelu(W1.s+b1)+b2).
// s and t both plain bf16 -> GEMM1/GEMM2 are 2-term (weights stay split).
// sB/tB: [pix][ch-pair] u32, stride 33. oT aliases sB. LDS 25856 B ->
// 6 blocks/CU. last==1: fused decoder straight to d_out (red aliases tB).
// ---------------------------------------------------------------------------
union FfnSmem {
    unsigned int sB[64 * 33];   // 8448 B, staged bf16 s tile
    float oT[64 * 68];          // 17408 B, epilogue2 transpose tile
};

__global__ __launch_bounds__(256, 6) void k_ffn2m(const unsigned short* __restrict__ in, unsigned short* __restrict__ out,
                                                  const short* __restrict__ w1f, const float* __restrict__ b1v,
                                                  const short* __restrict__ w2f, const float* __restrict__ b2v,
                                                  const float* __restrict__ Wd, const float* __restrict__ bd,
                                                  float* __restrict__ dout, int last) {
    __shared__ __align__(16) FfnSmem u;
    __shared__ __align__(16) unsigned int tB[64 * 33];
    int t = threadIdx.x;
    int pixBase = blockIdx.x * 64;
    int lane15 = t & 15;
    int quad   = (t >> 4) & 3;
    int wv     = t >> 6;
    int row    = wv * 16 + lane15;
    int pix0 = (t & 15) * 4;                   // RMW pixel base
    int c0 = (t >> 4) * 4;                     // RMW channel base

    // ---- independent loads up front: h residual prefetch (bf16) + s tile ----
    uint2 hr[4];
    #pragma unroll
    for (int i = 0; i < 4; ++i)
        hr[i] = *(const uint2*)(out + (size_t)(c0 + i) * NPIX + pixBase + pix0);
    {
        int k  = t >> 3;                       // channel pair 0..31
        int po = t & 7;                        // pixel oct
        const uint4* r0 = (const uint4*)(in + (size_t)(2 * k) * NPIX + pixBase) + po;
        const uint4* r1 = (const uint4*)(in + (size_t)(2 * k + 1) * NPIX + pixBase) + po;
        uint4 a = *r0, b = *r1;
        unsigned int aw[4] = {a.x, a.y, a.z, a.w};
        unsigned int bw[4] = {b.x, b.y, b.z, b.w};
        #pragma unroll
        for (int i = 0; i < 4; ++i) {
            int pix = po * 8 + 2 * i;
            u.sB[pix * 33 + k]       = (aw[i] & 0xffffu) | (bw[i] << 16);
            u.sB[(pix + 1) * 33 + k] = (aw[i] >> 16) | (bw[i] & 0xffff0000u);
        }
    }

    short8 W1h[8], W1l[8];
    #pragma unroll
    for (int s8 = 0; s8 < 8; ++s8) {
        const short8* p = (const short8*)(w1f + (((size_t)s8 * 64 + (t & 63)) << 4));
        W1h[s8] = p[0]; W1l[s8] = p[1];
    }

    f32x4 acc[4];
    #pragma unroll
    for (int mt = 0; mt < 4; ++mt) acc[mt] = (f32x4){0.f, 0.f, 0.f, 0.f};

    __syncthreads();

    // ---- GEMM1: 2-term ----
    #pragma unroll
    for (int kc = 0; kc < 2; ++kc) {
        union { unsigned int w[4]; short8 v; } bb;
        #pragma unroll
        for (int i = 0; i < 4; ++i)
            bb.w[i] = u.sB[row * 33 + kc * 16 + quad * 4 + i];
        #pragma unroll
        for (int mt = 0; mt < 4; ++mt) {
            int s8 = mt * 2 + kc;
            acc[mt] = MFMA16(W1h[s8], bb.v, acc[mt]);
            acc[mt] = MFMA16(W1l[s8], bb.v, acc[mt]);
        }
    }

    // ---- epilogue1: gelu -> plain bf16 pairs -> tB ----
    #pragma unroll
    for (int mt = 0; mt < 4; ++mt) {
        const float* bp = b1v + mt * 16 + quad * 4;
        float g[4];
        #pragma unroll
        for (int r = 0; r < 4; ++r) g[r] = gelu_f(acc[mt][r] + bp[r]);
        int cp = (mt * 16 + quad * 4) >> 1;    // channel-pair index (even)
        tB[row * 33 + cp]     = (unsigned int)bf16_rne(g[0]) | ((unsigned int)bf16_rne(g[1]) << 16);
        tB[row * 33 + cp + 1] = (unsigned int)bf16_rne(g[2]) | ((unsigned int)bf16_rne(g[3]) << 16);
        acc[mt] = (f32x4){0.f, 0.f, 0.f, 0.f};
    }

    short8 W2h[8], W2l[8];
    #pragma unroll
    for (int s8 = 0; s8 < 8; ++s8) {
        const short8* p = (const short8*)(w2f + (((size_t)s8 * 64 + (t & 63)) << 4));
        W2h[s8] = p[0]; W2l[s8] = p[1];
    }

    __syncthreads();   // tB visible; fences GEMM1 sB reads (oT may alias)

    // ---- GEMM2: 2-term ----
    #pragma unroll
    for (int kc = 0; kc < 2; ++kc) {
        union { unsigned int w[4]; short8 v; } bb;
        #pragma unroll
        for (int i = 0; i < 4; ++i)
            bb.w[i] = tB[row * 33 + kc * 16 + quad * 4 + i];
        #pragma unroll
        for (int mt = 0; mt < 4; ++mt) {
            int s8 = mt * 2 + kc;
            acc[mt] = MFMA16(W2h[s8], bb.v, acc[mt]);
            acc[mt] = MFMA16(W2l[s8], bb.v, acc[mt]);
        }
    }

    // ---- epilogue2: gelu -> oT (aliases sB) ----
    #pragma unroll
    for (int mt = 0; mt < 4; ++mt) {
        const float* bp = b2v + mt * 16 + quad * 4;
        #pragma unroll
        for (int r = 0; r < 4; ++r) {
            int o = mt * 16 + quad * 4 + r;
            u.oT[o * 68 + row] = gelu_f(acc[mt][r] + bp[r]);
        }
    }
    __syncthreads();

    if (!last) {
        // ---- h(bf16) += increment (prefetched residual) ----
        #pragma unroll
        for (int i = 0; i < 4; ++i) {
            int c = c0 + i;
            float4 gv = *(const float4*)&u.oT[c * 68 + pix0];
            float f0 = bf16_tof((unsigned short)(hr[i].x & 0xffffu)) + gv.x;
            float f1 = bf16_tof((unsigned short)(hr[i].x >> 16))     + gv.y;
            float f2 = bf16_tof((unsigned short)(hr[i].y & 0xffffu)) + gv.z;
            float f3 = bf16_tof((unsigned short)(hr[i].y >> 16))     + gv.w;
            uint2 o;
            o.x = (unsigned int)bf16_rne(f0) | ((unsigned int)bf16_rne(f1) << 16);
            o.y = (unsigned int)bf16_rne(f2) | ((unsigned int)bf16_rne(f3) << 16);
            *(uint2*)(out + (size_t)c * NPIX + pixBase + pix0) = o;
        }
    } else {
        // ---- fused decoder: dout = sum_c Wd[c]*(hres+gv) + bd (red aliases dead tB) ----
        float* red = (float*)tB;               // 16 grp x 65 stride x 64 pix fits (4160 B)
        float part[4] = {0.f, 0.f, 0.f, 0.f};
        #pragma unroll
        for (int i = 0; i < 4; ++i) {
            int c = c0 + i;
            float wd = Wd[c];
            float4 gv = *(const float4*)&u.oT[c * 68 + pix0];
            part[0] += wd * (bf16_tof((unsigned short)(hr[i].x & 0xffffu)) + gv.x);
            part[1] += wd * (bf16_tof((unsigned short)(hr[i].x >> 16))     + gv.y);
            part[2] += wd * (bf16_tof((unsigned short)(hr[i].y & 0xffffu)) + gv.z);
            part[3] += wd * (bf16_tof((unsigned short)(hr[i].y >> 16))     + gv.w);
        }
        __syncthreads();   // tB GEMM2 reads done before aliasing as red
        int g = t >> 4;
        #pragma unroll
        for (int j = 0; j < 4; ++j)
            red[g * 65 + pix0 + j] = part[j];
        __syncthreads();
        if (t < 64) {
            float sum = bd[0];
            #pragma unroll
            for (int gg = 0; gg < 16; ++gg)
                sum += red[gg * 65 + t];
            dout[pixBase + t] = sum;
        }
    }
}

extern "C" void kernel_launch(void* const* d_in, const int* in_sizes, int n_in,
                              void* d_out, int out_size, void* d_ws, size_t ws_size,
                              hipStream_t stream) {
    (void)in_sizes; (void)n_in; (void)out_size; (void)ws_size;
    const float* u   = (const float*)d_in[0];
    const float* xc  = (const float*)d_in[1];
    const float* We  = (const float*)d_in[2];
    const float* be  = (const float*)d_in[3];
    const float* W1  = (const float*)d_in[4];
    const float* b1  = (const float*)d_in[5];
    const float* W2  = (const float*)d_in[6];
    const float* b2  = (const float*)d_in[7];
    const float* Are = (const float*)d_in[8];
    const float* Aim = (const float*)d_in[9];
    const float* Wd  = (const float*)d_in[10];
    const float* bd  = (const float*)d_in[11];

    // workspace layout, ~93 MB used
    char* ws = (char*)d_ws;
    unsigned short* h = (unsigned short*)ws;                  // 32 MB (bf16)
    unsigned short* s = (unsigned short*)(ws + (size_t)33554432); // 32 MB (bf16)
    float* VfH = (float*)(ws + (size_t)67108864);             // 4 MB: [64][32][512]
    float* VfW = VfH + (size_t)1048576;                       // 4 MB
    float* VmH = VfW + (size_t)1048576;                       // 4 MB: [64][512][32]
    float* VmW = VmH + (size_t)1048576;                       // 4 MB
    short* FbB = (short*)(VmW + 1048576);                     // 64 KB
    short* GbF = FbB + 32768;                                 // 64 KB
    short* Am  = GbF + 32768;                                 // 6 MB
    short* Wpk = Am  + (size_t)65536 * 48;                    // 128 KB

    k_setup<<<1312, 256, 0, stream>>>(W1, W2, Are, Aim, u, xc, We, be,
                                      FbB, GbF, Wpk, Am, h);

    for (int l = 0; l < 4; ++l) {
        k_fwd<<<dim3(8, 64, 2), 256, 0, stream>>>(h, FbB, VfH, VfW);
        k_mix2<<<512, 256, 0, stream>>>(VfH, VfW, Am + (size_t)(l * 2) * ASLAB, VmH, VmW);
        k_inv<<<dim3(8, 8, 64), 256, 0, stream>>>(VmW, VmH, GbF, s);
        k_ffn2m<<<4096, 256, 0, stream>>>(s, h,
                                          Wpk + (size_t)(l * 2 + 0) * 8192, b1 + (size_t)l * 64,
                                          Wpk + (size_t)(l * 2 + 1) * 8192, b2 + (size_t)l * 64,
                                          Wd, bd, (float*)d_out, (l == 3) ? 1 : 0);
    }
}

// Round 13
// 503.101 us; speedup vs baseline: 1.7554x; 1.0438x over previous
//
#include <hip/hip_runtime.h>

#define NPIX (512*512)

typedef __attribute__((ext_vector_type(8))) short short8;   // 8 bf16 in 4 VGPRs
typedef __attribute__((ext_vector_type(4))) float f32x4;    // MFMA accumulator

#define MFMA16(A, B, C) __builtin_amdgcn_mfma_f32_16x16x32_bf16((A), (B), (C), 0, 0, 0)

// JAX gelu(approximate=True): x * sigmoid(2*sqrt(2/pi)*(x+0.044715x^3)); inf-safe.
__device__ __forceinline__ float gelu_f(float x) {
    return x / (1.0f + __expf(-1.5957691216057308f * (x + 0.044715f * x * x * x)));
}

// f32 -> bf16 bits (RNE)
__device__ __forceinline__ unsigned short bf16_rne(float x) {
    unsigned int b = __float_as_uint(x);
    unsigned int r = b + 0x7fffu + ((b >> 16) & 1u);
    return (unsigned short)(r >> 16);
}
__device__ __forceinline__ float bf16_tof(unsigned short h) {
    return __uint_as_float(((unsigned int)h) << 16);
}
__device__ __forceinline__ unsigned int bf16_split_pack(float x) {
    unsigned short hi = bf16_rne(x);
    unsigned short lo = bf16_rne(x - bf16_tof(hi));
    return (unsigned int)hi | ((unsigned int)lo << 16);
}
__device__ __forceinline__ void split8(const float* x, short8& h, short8& l) {
    #pragma unroll
    for (int j = 0; j < 8; ++j) {
        unsigned short hi = bf16_rne(x[j]);
        h[j] = (short)hi;
        l[j] = (short)bf16_rne(x[j] - bf16_tof(hi));
    }
}
// unzip 8 split-packed u32 (hi|lo<<16 per elem) -> hi-short8 / lo-short8
__device__ __forceinline__ void unzip8(const unsigned int* w, short8& h, short8& l) {
    union { unsigned int u[4]; short8 v; } hh, ll;
    #pragma unroll
    for (int i = 0; i < 4; ++i) {
        hh.u[i] = (w[2*i] & 0xffffu) | (w[2*i+1] << 16);
        ll.u[i] = (w[2*i] >> 16) | (w[2*i+1] & 0xffff0000u);
    }
    h = hh.v; l = ll.v;
}

#define ASLAB ((size_t)16 * 4 * 2 * 64 * 48)   // shorts per (l,ax) in Am

// ---------------------------------------------------------------------------
// Merged setup + encoder: blocks 0..15 basis tables, 16..31 FFN weights,
// 32..287 spectral A-weights, 288..1311 encoder (h stored bf16).
// ---------------------------------------------------------------------------
__global__ __launch_bounds__(256) void k_setup(const float* __restrict__ W1, const float* __restrict__ W2,
                                               const float* __restrict__ Are, const float* __restrict__ Aim,
                                               const float* __restrict__ u, const float* __restrict__ xc,
                                               const float* __restrict__ We, const float* __restrict__ be,
                                               short* __restrict__ FbB, short* __restrict__ GbF,
                                               short* __restrict__ Wpk, short* __restrict__ Am,
                                               unsigned short* __restrict__ h) {
    int b = blockIdx.x;
    int t = threadIdx.x;
    if (b < 16) {
        int id = b * 256 + t;
        int lane = id & 63;
        int quad = lane >> 4, l15 = lane & 15;
        short* dst;
        int n0, nstep, o0, ostep;
        float wscale = 1.0f;
        if (id < 2048) {
            int nt = (id >> 6) & 1, kc = id >> 7;
            dst = FbB + id * 16;
            n0 = kc * 32 + quad * 8; nstep = 1;
            o0 = nt * 16 + l15;      ostep = 0;
        } else {
            int id2 = id - 2048;
            dst = GbF + id2 * 16;
            int tt = id2 >> 6;
            n0 = tt * 16 + l15;      nstep = 0;
            o0 = quad * 8;           ostep = 1;
            wscale = 1.0f / 512.0f;
        }
        #pragma unroll
        for (int j = 0; j < 8; ++j) {
            int n = n0 + nstep * j;
            int o = o0 + ostep * j;
            int m = o >> 1, ri = o & 1;
            int k = (n * m) & 511;
            float sv, cv;
            sincosf(6.283185307179586f * (1.0f / 512.0f) * (float)k, &sv, &cv);
            float v = ri ? -sv : cv;
            if (id >= 2048) v *= (m == 0 ? 1.0f : 2.0f) * wscale;
            unsigned short hi = bf16_rne(v);
            dst[j]     = (short)hi;
            dst[8 + j] = (short)bf16_rne(v - bf16_tof(hi));
        }
    } else if (b < 32) {
        int tid = (b - 16) * 256 + t;
        int lane = tid & 63;
        int kc = (tid >> 6) & 1;
        int mt = (tid >> 7) & 3;
        int wg = tid >> 9;
        int layer = wg >> 1, which = wg & 1;
        const float* Wsrc = (which ? W2 : W1) + (size_t)layer * 4096;
        int o  = mt * 16 + (lane & 15);
        int c0 = kc * 32 + ((lane >> 4) & 3) * 8;
        short* dst = Wpk + (size_t)tid * 16;
        #pragma unroll
        for (int j = 0; j < 8; ++j) {
            float x = Wsrc[o * 64 + c0 + j];
            unsigned short hi = bf16_rne(x);
            dst[j]     = (short)hi;
            dst[8 + j] = (short)bf16_rne(x - bf16_tof(hi));
        }
    } else if (b < 288) {
        int id = (b - 32) * 256 + t;
        int lane = id & 63;
        int kc  = (id >> 6) & 1;
        int mt  = (id >> 7) & 3;
        int m   = (id >> 9) & 15;
        int lax = id >> 13;
        int l = lax >> 1, ax = lax & 1;
        int o  = mt * 16 + (lane & 15);
        int i0 = kc * 32 + ((lane >> 4) & 3) * 8;
        short* dst = Am + (size_t)id * 48;
        #pragma unroll
        for (int j = 0; j < 8; ++j) {
            size_t src = (((size_t)(l * 64 + o) * 64 + (i0 + j)) * 16 + m) * 2 + ax;
            float ar = Are[src], ai = Aim[src];
            unsigned short hh;
            hh = bf16_rne(ar);  dst[j]      = (short)hh; dst[8 + j]  = (short)bf16_rne(ar - bf16_tof(hh));
            hh = bf16_rne(ai);  dst[16 + j] = (short)hh; dst[24 + j] = (short)bf16_rne(ai - bf16_tof(hh));
            hh = bf16_rne(-ai); dst[32 + j] = (short)hh; dst[40 + j] = (short)bf16_rne(-ai - bf16_tof(hh));
        }
    } else {
        // encoder: h[p][pix] = bf16(We.x + be)
        int pix = (b - 288) * 256 + t;
        float x0 = xc[pix], x1 = xc[NPIX + pix], uu = u[pix];
        #pragma unroll 8
        for (int p = 0; p < 64; ++p) {
            float v = We[p * 3] * x0 + We[p * 3 + 1] * x1 + We[p * 3 + 2] * uu + be[p];
            h[(size_t)p * NPIX + pix] = bf16_rne(v);
        }
    }
}

// ---------------------------------------------------------------------------
// Merged forward DFT, both axes, h in bf16 (B-frag direct reinterpret; A-side
// basis split -> 2-term MFMA). grid(8 ntile, 64 p, 2 axis), block 256.
// ---------------------------------------------------------------------------
__global__ __launch_bounds__(256) void k_fwd(const unsigned short* __restrict__ h, const short* __restrict__ FbB,
                                             float* __restrict__ VfH, float* __restrict__ VfW) {
    int t = threadIdx.x;
    int ntb = blockIdx.x, p = blockIdx.y, axis = blockIdx.z;
    int wv = t >> 6, lane = t & 63, quad = lane >> 4, l15 = lane & 15;
    int n = ntb * 64 + wv * 16 + l15;
    f32x4 acc[2];
    acc[0] = (f32x4){0.f,0.f,0.f,0.f}; acc[1] = (f32x4){0.f,0.f,0.f,0.f};
    #pragma unroll 4
    for (int kc = 0; kc < 16; ++kc) {
        int kb = kc * 32 + quad * 8;
        short8 Bv;
        if (axis == 0) {
            const unsigned short* hp = h + ((size_t)p * 512 + kb) * 512 + n;
            #pragma unroll
            for (int j = 0; j < 8; ++j) Bv[j] = (short)hp[(size_t)j * 512];
        } else {
            const unsigned short* hp = h + ((size_t)p * 512 + n) * 512 + kb;
            Bv = *(const short8*)hp;
        }
        #pragma unroll
        for (int mt = 0; mt < 2; ++mt) {
            const short8* ap = (const short8*)(FbB + (((kc * 2 + mt) * 64 + lane) << 4));
            short8 Ah = ap[0], Al = ap[1];
            acc[mt] = MFMA16(Ah, Bv, acc[mt]);
            acc[mt] = MFMA16(Al, Bv, acc[mt]);
        }
    }
    float* vp = (axis ? VfW : VfH) + (size_t)p * 32 * 512;
    #pragma unroll
    for (int mt = 0; mt < 2; ++mt)
        #pragma unroll
        for (int r = 0; r < 4; ++r)
            vp[(size_t)(mt * 16 + quad * 4 + r) * 512 + n] = acc[mt][r];
}

// ---------------------------------------------------------------------------
// Merged mode mixing, both axes. Epilogue writes Vm SPLIT-PACKED u32
// (hi|lo<<16 per component; same 4 B, bit-identical to inv's old split8).
// grid 512 (axis = bid>>8; m = bid&15, otile = (bid>>4)&15), block 256.
// ---------------------------------------------------------------------------
__global__ __launch_bounds__(256) void k_mix2(const float* __restrict__ VfH, const float* __restrict__ VfW,
                                              const short* __restrict__ AmL,
                                              unsigned int* __restrict__ VmH, unsigned int* __restrict__ VmW) {
    __shared__ unsigned int BT[2 * 64 * 33];
    int bid = blockIdx.x;
    int axis = bid >> 8;
    int m  = bid & 15;
    int ot = (bid >> 4) & 15;
    const float* Vf = axis ? VfW : VfH;
    unsigned int* Vm = axis ? VmW : VmH;
    const short* Am = AmL + (size_t)axis * ASLAB;
    int t = threadIdx.x;
    #pragma unroll
    for (int it = 0; it < 16; ++it) {
        int idx = it * 256 + t;
        int oth = idx & 31, ri = (idx >> 5) & 1, i = idx >> 6;
        float v = Vf[((size_t)i * 32 + m * 2 + ri) * 512 + ot * 32 + oth];
        BT[(ri * 64 + i) * 33 + oth] = bf16_split_pack(v);
    }
    __syncthreads();
    int wv = t >> 6, lane = t & 63, quad = lane >> 4, l15 = lane & 15;
    int nt = wv & 1, mtp = wv >> 1;
    f32x4 aR[2], aI[2];
    aR[0]=(f32x4){0.f,0.f,0.f,0.f}; aR[1]=aR[0]; aI[0]=aR[0]; aI[1]=aR[0];
    #pragma unroll
    for (int kc = 0; kc < 2; ++kc) {
        short8 Brh, Brl, Bih, Bil;
        #pragma unroll
        for (int j = 0; j < 8; ++j) {
            int i = kc * 32 + quad * 8 + j;
            unsigned int br = BT[i * 33 + nt * 16 + l15];
            unsigned int bi = BT[(64 + i) * 33 + nt * 16 + l15];
            Brh[j] = (short)(br & 0xffffu); Brl[j] = (short)(br >> 16);
            Bih[j] = (short)(bi & 0xffffu); Bil[j] = (short)(bi >> 16);
        }
        #pragma unroll
        for (int mi = 0; mi < 2; ++mi) {
            int mt = mtp * 2 + mi;
            const short8* ap = (const short8*)(Am + ((size_t)(((m * 4 + mt) * 2 + kc) * 64 + lane)) * 48);
            short8 Arh = ap[0], Arl = ap[1], Aih = ap[2], Ail = ap[3], Anh = ap[4], Anl = ap[5];
            aR[mi] = MFMA16(Arh, Brh, aR[mi]);
            aR[mi] = MFMA16(Arl, Brh, aR[mi]);
            aR[mi] = MFMA16(Arh, Brl, aR[mi]);
            aR[mi] = MFMA16(Anh, Bih, aR[mi]);
            aR[mi] = MFMA16(Anl, Bih, aR[mi]);
            aR[mi] = MFMA16(Anh, Bil, aR[mi]);
            aI[mi] = MFMA16(Arh, Bih, aI[mi]);
            aI[mi] = MFMA16(Arl, Bih, aI[mi]);
            aI[mi] = MFMA16(Arh, Bil, aI[mi]);
            aI[mi] = MFMA16(Aih, Brh, aI[mi]);
            aI[mi] = MFMA16(Ail, Brh, aI[mi]);
            aI[mi] = MFMA16(Aih, Brl, aI[mi]);
        }
    }
    int oth = ot * 32 + nt * 16 + l15;
    #pragma unroll
    for (int mi = 0; mi < 2; ++mi) {
        int o = (mtp * 2 + mi) * 16 + quad * 4;
        #pragma unroll
        for (int r = 0; r < 4; ++r) {
            uint2 v;
            v.x = bf16_split_pack(aR[mi][r]);
            v.y = bf16_split_pack(aI[mi][r]);
            *(uint2*)(Vm + ((size_t)(o + r) * 512 + oth) * 32 + m * 2) = v;
        }
    }
}

// ---------------------------------------------------------------------------
// Fused inverse DFT (both axes) -> s as PLAIN BF16 (2 B). Vm arrives
// split-packed: frag build is cheap unzip (no split8 chains).
// grid(8 wt, 8 yt, 64 p), block 256.
// ---------------------------------------------------------------------------
__global__ __launch_bounds__(256) void k_inv(const unsigned int* __restrict__ VmW, const unsigned int* __restrict__ VmH,
                                             const short* __restrict__ GbF, unsigned short* __restrict__ s) {
    int t = threadIdx.x;
    int wt = blockIdx.x, yt = blockIdx.y, p = blockIdx.z;
    int wv = t >> 6, lane = t & 63, quad = lane >> 4, l15 = lane & 15;
    int ys = yt * 64 + wv * 16;
    const uint4* a2p = (const uint4*)(VmW + ((size_t)p * 512 + ys + l15) * 32 + quad * 8);
    unsigned int aw[8];
    {
        uint4 x0 = a2p[0], x1 = a2p[1];
        aw[0]=x0.x; aw[1]=x0.y; aw[2]=x0.z; aw[3]=x0.w;
        aw[4]=x1.x; aw[5]=x1.y; aw[6]=x1.z; aw[7]=x1.w;
    }
    short8 A2h, A2l; unzip8(aw, A2h, A2l);
    const short8* g1 = (const short8*)(GbF + (((yt * 4 + wv) * 64 + lane) << 4));
    short8 A1h = g1[0], A1l = g1[1];
    #pragma unroll
    for (int nt = 0; nt < 4; ++nt) {
        int wb = wt * 64 + nt * 16;
        const uint4* b1p = (const uint4*)(VmH + ((size_t)p * 512 + wb + l15) * 32 + quad * 8);
        unsigned int bw[8];
        uint4 x0 = b1p[0], x1 = b1p[1];
        bw[0]=x0.x; bw[1]=x0.y; bw[2]=x0.z; bw[3]=x0.w;
        bw[4]=x1.x; bw[5]=x1.y; bw[6]=x1.z; bw[7]=x1.w;
        short8 B1h, B1l; unzip8(bw, B1h, B1l);
        const short8* g2 = (const short8*)(GbF + (((wt * 4 + nt) * 64 + lane) << 4));
        short8 B2h = g2[0], B2l = g2[1];
        f32x4 acc = (f32x4){0.f,0.f,0.f,0.f};
        acc = MFMA16(A1h, B1h, acc);
        acc = MFMA16(A1l, B1h, acc);
        acc = MFMA16(A1h, B1l, acc);
        acc = MFMA16(A2h, B2h, acc);
        acc = MFMA16(A2l, B2h, acc);
        acc = MFMA16(A2h, B2l, acc);
        #pragma unroll
        for (int r = 0; r < 4; ++r)
            s[((size_t)p * 512 + ys + quad * 4 + r) * 512 + wb + l15] = bf16_rne(acc[r]);
    }
}

// ---------------------------------------------------------------------------
// MFMA FFN (single-tile, grid 4096): h(bf16) += gelu(W2.gelu(W1.s+b1)+b2).
// GEMM1/GEMM2 2-term. RMW mapping = 2ch x 8px so h loads/stores are uint4
// (16 B; R12's 8 B uint2 caused write amplification, WRITE 65->73 MB).
// LDS 25856 B -> 6 blocks/CU. last==1: fused decoder to d_out.
// ---------------------------------------------------------------------------
union FfnSmem {
    unsigned int sB[64 * 33];   // 8448 B, staged bf16 s tile
    float oT[64 * 68];          // 17408 B, epilogue2 transpose tile
};

__global__ __launch_bounds__(256, 6) void k_ffn2m(const unsigned short* __restrict__ in, unsigned short* __restrict__ out,
                                                  const short* __restrict__ w1f, const float* __restrict__ b1v,
                                                  const short* __restrict__ w2f, const float* __restrict__ b2v,
                                                  const float* __restrict__ Wd, const float* __restrict__ bd,
                                                  float* __restrict__ dout, int last) {
    __shared__ __align__(16) FfnSmem u;
    __shared__ __align__(16) unsigned int tB[64 * 33];
    int t = threadIdx.x;
    int pixBase = blockIdx.x * 64;
    int lane15 = t & 15;
    int quad   = (t >> 4) & 3;
    int wv     = t >> 6;
    int row    = wv * 16 + lane15;
    int pix0 = (t & 7) * 8;                    // RMW pixel base (8 px -> uint4)
    int c0   = (t >> 3) * 2;                   // RMW channel base (2 ch)

    // ---- independent loads up front: h residual prefetch (uint4) + s tile ----
    uint4 hr[2];
    #pragma unroll
    for (int i = 0; i < 2; ++i)
        hr[i] = *(const uint4*)(out + (size_t)(c0 + i) * NPIX + pixBase + pix0);
    {
        int k  = t >> 3;                       // channel pair 0..31
        int po = t & 7;                        // pixel oct
        const uint4* r0 = (const uint4*)(in + (size_t)(2 * k) * NPIX + pixBase) + po;
        const uint4* r1 = (const uint4*)(in + (size_t)(2 * k + 1) * NPIX + pixBase) + po;
        uint4 a = *r0, b = *r1;
        unsigned int aw[4] = {a.x, a.y, a.z, a.w};
        unsigned int bw[4] = {b.x, b.y, b.z, b.w};
        #pragma unroll
        for (int i = 0; i < 4; ++i) {
            int pix = po * 8 + 2 * i;
            u.sB[pix * 33 + k]       = (aw[i] & 0xffffu) | (bw[i] << 16);
            u.sB[(pix + 1) * 33 + k] = (aw[i] >> 16) | (bw[i] & 0xffff0000u);
        }
    }

    short8 W1h[8], W1l[8];
    #pragma unroll
    for (int s8 = 0; s8 < 8; ++s8) {
        const short8* p = (const short8*)(w1f + (((size_t)s8 * 64 + (t & 63)) << 4));
        W1h[s8] = p[0]; W1l[s8] = p[1];
    }

    f32x4 acc[4];
    #pragma unroll
    for (int mt = 0; mt < 4; ++mt) acc[mt] = (f32x4){0.f, 0.f, 0.f, 0.f};

    __syncthreads();

    // ---- GEMM1: 2-term ----
    #pragma unroll
    for (int kc = 0; kc < 2; ++kc) {
        union { unsigned int w[4]; short8 v; } bb;
        #pragma unroll
        for (int i = 0; i < 4; ++i)
            bb.w[i] = u.sB[row * 33 + kc * 16 + quad * 4 + i];
        #pragma unroll
        for (int mt = 0; mt < 4; ++mt) {
            int s8 = mt * 2 + kc;
            acc[mt] = MFMA16(W1h[s8], bb.v, acc[mt]);
            acc[mt] = MFMA16(W1l[s8], bb.v, acc[mt]);
        }
    }

    // ---- epilogue1: gelu -> plain bf16 pairs -> tB ----
    #pragma unroll
    for (int mt = 0; mt < 4; ++mt) {
        const float* bp = b1v + mt * 16 + quad * 4;
        float g[4];
        #pragma unroll
        for (int r = 0; r < 4; ++r) g[r] = gelu_f(acc[mt][r] + bp[r]);
        int cp = (mt * 16 + quad * 4) >> 1;
        tB[row * 33 + cp]     = (unsigned int)bf16_rne(g[0]) | ((unsigned int)bf16_rne(g[1]) << 16);
        tB[row * 33 + cp + 1] = (unsigned int)bf16_rne(g[2]) | ((unsigned int)bf16_rne(g[3]) << 16);
        acc[mt] = (f32x4){0.f, 0.f, 0.f, 0.f};
    }

    short8 W2h[8], W2l[8];
    #pragma unroll
    for (int s8 = 0; s8 < 8; ++s8) {
        const short8* p = (const short8*)(w2f + (((size_t)s8 * 64 + (t & 63)) << 4));
        W2h[s8] = p[0]; W2l[s8] = p[1];
    }

    __syncthreads();   // tB visible; fences GEMM1 sB reads (oT may alias)

    // ---- GEMM2: 2-term ----
    #pragma unroll
    for (int kc = 0; kc < 2; ++kc) {
        union { unsigned int w[4]; short8 v; } bb;
        #pragma unroll
        for (int i = 0; i < 4; ++i)
            bb.w[i] = tB[row * 33 + kc * 16 + quad * 4 + i];
        #pragma unroll
        for (int mt = 0; mt < 4; ++mt) {
            int s8 = mt * 2 + kc;
            acc[mt] = MFMA16(W2h[s8], bb.v, acc[mt]);
            acc[mt] = MFMA16(W2l[s8], bb.v, acc[mt]);
        }
    }

    // ---- epilogue2: gelu -> oT (aliases sB) ----
    #pragma unroll
    for (int mt = 0; mt < 4; ++mt) {
        const float* bp = b2v + mt * 16 + quad * 4;
        #pragma unroll
        for (int r = 0; r < 4; ++r) {
            int o = mt * 16 + quad * 4 + r;
            u.oT[o * 68 + row] = gelu_f(acc[mt][r] + bp[r]);
        }
    }
    __syncthreads();

    if (!last) {
        // ---- h(bf16) += increment: 2 ch x 8 px, uint4 stores ----
        #pragma unroll
        for (int i = 0; i < 2; ++i) {
            int c = c0 + i;
            float4 g0 = *(const float4*)&u.oT[c * 68 + pix0];
            float4 g1 = *(const float4*)&u.oT[c * 68 + pix0 + 4];
            unsigned int w[4] = {hr[i].x, hr[i].y, hr[i].z, hr[i].w};
            float f[8];
            f[0] = bf16_tof((unsigned short)(w[0] & 0xffffu)) + g0.x;
            f[1] = bf16_tof((unsigned short)(w[0] >> 16))     + g0.y;
            f[2] = bf16_tof((unsigned short)(w[1] & 0xffffu)) + g0.z;
            f[3] = bf16_tof((unsigned short)(w[1] >> 16))     + g0.w;
            f[4] = bf16_tof((unsigned short)(w[2] & 0xffffu)) + g1.x;
            f[5] = bf16_tof((unsigned short)(w[2] >> 16))     + g1.y;
            f[6] = bf16_tof((unsigned short)(w[3] & 0xffffu)) + g1.z;
            f[7] = bf16_tof((unsigned short)(w[3] >> 16))     + g1.w;
            uint4 o;
            o.x = (unsigned int)bf16_rne(f[0]) | ((unsigned int)bf16_rne(f[1]) << 16);
            o.y = (unsigned int)bf16_rne(f[2]) | ((unsigned int)bf16_rne(f[3]) << 16);
            o.z = (unsigned int)bf16_rne(f[4]) | ((unsigned int)bf16_rne(f[5]) << 16);
            o.w = (unsigned int)bf16_rne(f[6]) | ((unsigned int)bf16_rne(f[7]) << 16);
            *(uint4*)(out + (size_t)c * NPIX + pixBase + pix0) = o;
        }
    } else {
        // ---- fused decoder: dout = sum_c Wd[c]*(hres+gv) + bd ----
        float part[8] = {0.f,0.f,0.f,0.f,0.f,0.f,0.f,0.f};
        #pragma unroll
        for (int i = 0; i < 2; ++i) {
            int c = c0 + i;
            float wd = Wd[c];
            float4 g0 = *(const float4*)&u.oT[c * 68 + pix0];
            float4 g1 = *(const float4*)&u.oT[c * 68 + pix0 + 4];
            unsigned int w[4] = {hr[i].x, hr[i].y, hr[i].z, hr[i].w};
            part[0] += wd * (bf16_tof((unsigned short)(w[0] & 0xffffu)) + g0.x);
            part[1] += wd * (bf16_tof((unsigned short)(w[0] >> 16))     + g0.y);
            part[2] += wd * (bf16_tof((unsigned short)(w[1] & 0xffffu)) + g0.z);
            part[3] += wd * (bf16_tof((unsigned short)(w[1] >> 16))     + g0.w);
            part[4] += wd * (bf16_tof((unsigned short)(w[2] & 0xffffu)) + g1.x);
            part[5] += wd * (bf16_tof((unsigned short)(w[2] >> 16))     + g1.y);
            part[6] += wd * (bf16_tof((unsigned short)(w[3] & 0xffffu)) + g1.z);
            part[7] += wd * (bf16_tof((unsigned short)(w[3] >> 16))     + g1.w);
        }
        __syncthreads();   // tB GEMM2 reads done before aliasing as red
        float* red = (float*)tB;               // 32 grp x 65 stride: 8320 B fits tB
        int g = t >> 3;                        // channel-pair group 0..31
        #pragma unroll
        for (int j = 0; j < 8; ++j)
            red[g * 65 + pix0 + j] = part[j];
        __syncthreads();
        if (t < 64) {
            float sum = bd[0];
            #pragma unroll
            for (int gg = 0; gg < 32; ++gg)
                sum += red[gg * 65 + t];
            dout[pixBase + t] = sum;
        }
    }
}

extern "C" void kernel_launch(void* const* d_in, const int* in_sizes, int n_in,
                              void* d_out, int out_size, void* d_ws, size_t ws_size,
                              hipStream_t stream) {
    (void)in_sizes; (void)n_in; (void)out_size; (void)ws_size;
    const float* u   = (const float*)d_in[0];
    const float* xc  = (const float*)d_in[1];
    const float* We  = (const float*)d_in[2];
    const float* be  = (const float*)d_in[3];
    const float* W1  = (const float*)d_in[4];
    const float* b1  = (const float*)d_in[5];
    const float* W2  = (const float*)d_in[6];
    const float* b2  = (const float*)d_in[7];
    const float* Are = (const float*)d_in[8];
    const float* Aim = (const float*)d_in[9];
    const float* Wd  = (const float*)d_in[10];
    const float* bd  = (const float*)d_in[11];

    // workspace layout, ~93 MB used
    char* ws = (char*)d_ws;
    unsigned short* h = (unsigned short*)ws;                  // 32 MB (bf16)
    unsigned short* s = (unsigned short*)(ws + (size_t)33554432); // 32 MB (bf16)
    float* VfH = (float*)(ws + (size_t)67108864);             // 4 MB: [64][32][512]
    float* VfW = VfH + (size_t)1048576;                       // 4 MB
    unsigned int* VmH = (unsigned int*)(VfW + 1048576);       // 4 MB split-packed
    unsigned int* VmW = VmH + (size_t)1048576;                // 4 MB
    short* FbB = (short*)(VmW + 1048576);                     // 64 KB
    short* GbF = FbB + 32768;                                 // 64 KB
    short* Am  = GbF + 32768;                                 // 6 MB
    short* Wpk = Am  + (size_t)65536 * 48;                    // 128 KB

    k_setup<<<1312, 256, 0, stream>>>(W1, W2, Are, Aim, u, xc, We, be,
                                      FbB, GbF, Wpk, Am, h);

    for (int l = 0; l < 4; ++l) {
        k_fwd<<<dim3(8, 64, 2), 256, 0, stream>>>(h, FbB, VfH, VfW);
        k_mix2<<<512, 256, 0, stream>>>(VfH, VfW, Am + (size_t)(l * 2) * ASLAB, VmH, VmW);
        k_inv<<<dim3(8, 8, 64), 256, 0, stream>>>(VmW, VmH, GbF, s);
        k_ffn2m<<<4096, 256, 0, stream>>>(s, h,
                                          Wpk + (size_t)(l * 2 + 0) * 8192, b1 + (size_t)l * 64,
                                          Wpk + (size_t)(l * 2 + 1) * 8192, b2 + (size_t)l * 64,
                                          Wd, bd, (float*)d_out, (l == 3) ? 1 : 0);
    }
}

// Round 14
// 498.365 us; speedup vs baseline: 1.7721x; 1.0095x over previous
//
#include <hip/hip_runtime.h>

#define NPIX (512*512)

typedef __attribute__((ext_vector_type(8))) short short8;   // 8 bf16 in 4 VGPRs
typedef __attribute__((ext_vector_type(4))) float f32x4;    // MFMA accumulator

#define MFMA16(A, B, C) __builtin_amdgcn_mfma_f32_16x16x32_bf16((A), (B), (C), 0, 0, 0)

// JAX gelu(approximate=True): x * sigmoid(2*sqrt(2/pi)*(x+0.044715x^3)); inf-safe.
__device__ __forceinline__ float gelu_f(float x) {
    return x / (1.0f + __expf(-1.5957691216057308f * (x + 0.044715f * x * x * x)));
}

// f32 -> bf16 bits (RNE)
__device__ __forceinline__ unsigned short bf16_rne(float x) {
    unsigned int b = __float_as_uint(x);
    unsigned int r = b + 0x7fffu + ((b >> 16) & 1u);
    return (unsigned short)(r >> 16);
}
__device__ __forceinline__ float bf16_tof(unsigned short h) {
    return __uint_as_float(((unsigned int)h) << 16);
}
__device__ __forceinline__ unsigned int bf16_split_pack(float x) {
    unsigned short hi = bf16_rne(x);
    unsigned short lo = bf16_rne(x - bf16_tof(hi));
    return (unsigned int)hi | ((unsigned int)lo << 16);
}
// unzip 8 split-packed u32 (hi|lo<<16 per elem) -> hi-short8 / lo-short8
__device__ __forceinline__ void unzip8(const unsigned int* w, short8& h, short8& l) {
    union { unsigned int u[4]; short8 v; } hh, ll;
    #pragma unroll
    for (int i = 0; i < 4; ++i) {
        hh.u[i] = (w[2*i] & 0xffffu) | (w[2*i+1] << 16);
        ll.u[i] = (w[2*i] >> 16) | (w[2*i+1] & 0xffff0000u);
    }
    h = hh.v; l = ll.v;
}

#define ASLAB ((size_t)16 * 4 * 2 * 64 * 48)   // shorts per (l,ax) in Am

// ---------------------------------------------------------------------------
// Merged setup + encoder: blocks 0..15 basis tables, 16..31 FFN weights,
// 32..287 spectral A-weights, 288..1311 encoder (h stored bf16).
// ---------------------------------------------------------------------------
__global__ __launch_bounds__(256) void k_setup(const float* __restrict__ W1, const float* __restrict__ W2,
                                               const float* __restrict__ Are, const float* __restrict__ Aim,
                                               const float* __restrict__ u, const float* __restrict__ xc,
                                               const float* __restrict__ We, const float* __restrict__ be,
                                               short* __restrict__ FbB, short* __restrict__ GbF,
                                               short* __restrict__ Wpk, short* __restrict__ Am,
                                               unsigned short* __restrict__ h) {
    int b = blockIdx.x;
    int t = threadIdx.x;
    if (b < 16) {
        int id = b * 256 + t;
        int lane = id & 63;
        int quad = lane >> 4, l15 = lane & 15;
        short* dst;
        int n0, nstep, o0, ostep;
        float wscale = 1.0f;
        if (id < 2048) {
            int nt = (id >> 6) & 1, kc = id >> 7;
            dst = FbB + id * 16;
            n0 = kc * 32 + quad * 8; nstep = 1;
            o0 = nt * 16 + l15;      ostep = 0;
        } else {
            int id2 = id - 2048;
            dst = GbF + id2 * 16;
            int tt = id2 >> 6;
            n0 = tt * 16 + l15;      nstep = 0;
            o0 = quad * 8;           ostep = 1;
            wscale = 1.0f / 512.0f;
        }
        #pragma unroll
        for (int j = 0; j < 8; ++j) {
            int n = n0 + nstep * j;
            int o = o0 + ostep * j;
            int m = o >> 1, ri = o & 1;
            int k = (n * m) & 511;
            float sv, cv;
            sincosf(6.283185307179586f * (1.0f / 512.0f) * (float)k, &sv, &cv);
            float v = ri ? -sv : cv;
            if (id >= 2048) v *= (m == 0 ? 1.0f : 2.0f) * wscale;
            unsigned short hi = bf16_rne(v);
            dst[j]     = (short)hi;
            dst[8 + j] = (short)bf16_rne(v - bf16_tof(hi));
        }
    } else if (b < 32) {
        int tid = (b - 16) * 256 + t;
        int lane = tid & 63;
        int kc = (tid >> 6) & 1;
        int mt = (tid >> 7) & 3;
        int wg = tid >> 9;
        int layer = wg >> 1, which = wg & 1;
        const float* Wsrc = (which ? W2 : W1) + (size_t)layer * 4096;
        int o  = mt * 16 + (lane & 15);
        int c0 = kc * 32 + ((lane >> 4) & 3) * 8;
        short* dst = Wpk + (size_t)tid * 16;
        #pragma unroll
        for (int j = 0; j < 8; ++j) {
            float x = Wsrc[o * 64 + c0 + j];
            unsigned short hi = bf16_rne(x);
            dst[j]     = (short)hi;
            dst[8 + j] = (short)bf16_rne(x - bf16_tof(hi));
        }
    } else if (b < 288) {
        int id = (b - 32) * 256 + t;
        int lane = id & 63;
        int kc  = (id >> 6) & 1;
        int mt  = (id >> 7) & 3;
        int m   = (id >> 9) & 15;
        int lax = id >> 13;
        int l = lax >> 1, ax = lax & 1;
        int o  = mt * 16 + (lane & 15);
        int i0 = kc * 32 + ((lane >> 4) & 3) * 8;
        short* dst = Am + (size_t)id * 48;
        #pragma unroll
        for (int j = 0; j < 8; ++j) {
            size_t src = (((size_t)(l * 64 + o) * 64 + (i0 + j)) * 16 + m) * 2 + ax;
            float ar = Are[src], ai = Aim[src];
            unsigned short hh;
            hh = bf16_rne(ar);  dst[j]      = (short)hh; dst[8 + j]  = (short)bf16_rne(ar - bf16_tof(hh));
            hh = bf16_rne(ai);  dst[16 + j] = (short)hh; dst[24 + j] = (short)bf16_rne(ai - bf16_tof(hh));
            hh = bf16_rne(-ai); dst[32 + j] = (short)hh; dst[40 + j] = (short)bf16_rne(-ai - bf16_tof(hh));
        }
    } else {
        // encoder: h[p][pix] = bf16(We.x + be)
        int pix = (b - 288) * 256 + t;
        float x0 = xc[pix], x1 = xc[NPIX + pix], uu = u[pix];
        #pragma unroll 8
        for (int p = 0; p < 64; ++p) {
            float v = We[p * 3] * x0 + We[p * 3 + 1] * x1 + We[p * 3 + 2] * uu + be[p];
            h[(size_t)p * NPIX + pix] = bf16_rne(v);
        }
    }
}

// ---------------------------------------------------------------------------
// Merged forward DFT, both axes, h in bf16 (B-frag direct reinterpret; A-side
// basis split -> 2-term MFMA). grid(64 p, 8 ntile, 2 axis): XCD keyed on p%8
// so all 8 w-tiles of channel p's column reads (128 B/row halves of 256-B
// sectors) land in ONE XCD's L2 (8 ch x 512 KB = 4 MB/XCD).
// ---------------------------------------------------------------------------
__global__ __launch_bounds__(256) void k_fwd(const unsigned short* __restrict__ h, const short* __restrict__ FbB,
                                             float* __restrict__ VfH, float* __restrict__ VfW) {
    int t = threadIdx.x;
    int p = blockIdx.x, ntb = blockIdx.y, axis = blockIdx.z;
    int wv = t >> 6, lane = t & 63, quad = lane >> 4, l15 = lane & 15;
    int n = ntb * 64 + wv * 16 + l15;
    f32x4 acc[2];
    acc[0] = (f32x4){0.f,0.f,0.f,0.f}; acc[1] = (f32x4){0.f,0.f,0.f,0.f};
    #pragma unroll 4
    for (int kc = 0; kc < 16; ++kc) {
        int kb = kc * 32 + quad * 8;
        short8 Bv;
        if (axis == 0) {
            const unsigned short* hp = h + ((size_t)p * 512 + kb) * 512 + n;
            #pragma unroll
            for (int j = 0; j < 8; ++j) Bv[j] = (short)hp[(size_t)j * 512];
        } else {
            const unsigned short* hp = h + ((size_t)p * 512 + n) * 512 + kb;
            Bv = *(const short8*)hp;
        }
        #pragma unroll
        for (int mt = 0; mt < 2; ++mt) {
            const short8* ap = (const short8*)(FbB + (((kc * 2 + mt) * 64 + lane) << 4));
            short8 Ah = ap[0], Al = ap[1];
            acc[mt] = MFMA16(Ah, Bv, acc[mt]);
            acc[mt] = MFMA16(Al, Bv, acc[mt]);
        }
    }
    float* vp = (axis ? VfW : VfH) + (size_t)p * 32 * 512;
    #pragma unroll
    for (int mt = 0; mt < 2; ++mt)
        #pragma unroll
        for (int r = 0; r < 4; ++r)
            vp[(size_t)(mt * 16 + quad * 4 + r) * 512 + n] = acc[mt][r];
}

// ---------------------------------------------------------------------------
// Merged mode mixing, both axes. Epilogue writes Vm SPLIT-PACKED u32.
// grid 512 (axis = bid>>8; m = bid&15, otile = (bid>>4)&15), block 256.
// ---------------------------------------------------------------------------
__global__ __launch_bounds__(256) void k_mix2(const float* __restrict__ VfH, const float* __restrict__ VfW,
                                              const short* __restrict__ AmL,
                                              unsigned int* __restrict__ VmH, unsigned int* __restrict__ VmW) {
    __shared__ unsigned int BT[2 * 64 * 33];
    int bid = blockIdx.x;
    int axis = bid >> 8;
    int m  = bid & 15;
    int ot = (bid >> 4) & 15;
    const float* Vf = axis ? VfW : VfH;
    unsigned int* Vm = axis ? VmW : VmH;
    const short* Am = AmL + (size_t)axis * ASLAB;
    int t = threadIdx.x;
    #pragma unroll
    for (int it = 0; it < 16; ++it) {
        int idx = it * 256 + t;
        int oth = idx & 31, ri = (idx >> 5) & 1, i = idx >> 6;
        float v = Vf[((size_t)i * 32 + m * 2 + ri) * 512 + ot * 32 + oth];
        BT[(ri * 64 + i) * 33 + oth] = bf16_split_pack(v);
    }
    __syncthreads();
    int wv = t >> 6, lane = t & 63, quad = lane >> 4, l15 = lane & 15;
    int nt = wv & 1, mtp = wv >> 1;
    f32x4 aR[2], aI[2];
    aR[0]=(f32x4){0.f,0.f,0.f,0.f}; aR[1]=aR[0]; aI[0]=aR[0]; aI[1]=aR[0];
    #pragma unroll
    for (int kc = 0; kc < 2; ++kc) {
        short8 Brh, Brl, Bih, Bil;
        #pragma unroll
        for (int j = 0; j < 8; ++j) {
            int i = kc * 32 + quad * 8 + j;
            unsigned int br = BT[i * 33 + nt * 16 + l15];
            unsigned int bi = BT[(64 + i) * 33 + nt * 16 + l15];
            Brh[j] = (short)(br & 0xffffu); Brl[j] = (short)(br >> 16);
            Bih[j] = (short)(bi & 0xffffu); Bil[j] = (short)(bi >> 16);
        }
        #pragma unroll
        for (int mi = 0; mi < 2; ++mi) {
            int mt = mtp * 2 + mi;
            const short8* ap = (const short8*)(Am + ((size_t)(((m * 4 + mt) * 2 + kc) * 64 + lane)) * 48);
            short8 Arh = ap[0], Arl = ap[1], Aih = ap[2], Ail = ap[3], Anh = ap[4], Anl = ap[5];
            aR[mi] = MFMA16(Arh, Brh, aR[mi]);
            aR[mi] = MFMA16(Arl, Brh, aR[mi]);
            aR[mi] = MFMA16(Arh, Brl, aR[mi]);
            aR[mi] = MFMA16(Anh, Bih, aR[mi]);
            aR[mi] = MFMA16(Anl, Bih, aR[mi]);
            aR[mi] = MFMA16(Anh, Bil, aR[mi]);
            aI[mi] = MFMA16(Arh, Bih, aI[mi]);
            aI[mi] = MFMA16(Arl, Bih, aI[mi]);
            aI[mi] = MFMA16(Arh, Bil, aI[mi]);
            aI[mi] = MFMA16(Aih, Brh, aI[mi]);
            aI[mi] = MFMA16(Ail, Brh, aI[mi]);
            aI[mi] = MFMA16(Aih, Brl, aI[mi]);
        }
    }
    int oth = ot * 32 + nt * 16 + l15;
    #pragma unroll
    for (int mi = 0; mi < 2; ++mi) {
        int o = (mtp * 2 + mi) * 16 + quad * 4;
        #pragma unroll
        for (int r = 0; r < 4; ++r) {
            uint2 v;
            v.x = bf16_split_pack(aR[mi][r]);
            v.y = bf16_split_pack(aI[mi][r]);
            *(uint2*)(Vm + ((size_t)(o + r) * 512 + oth) * 32 + m * 2) = v;
        }
    }
}

// ---------------------------------------------------------------------------
// Fused inverse DFT (both axes) -> s as PLAIN BF16 (2 B).
// grid(8 yt, 8 wt, 64 p): XCD keyed on yt so (a) adjacent wt write-halves of
// each 256-B s sector merge in one XCD's L2, (b) XCD x PRODUCES exactly the
// y-slice of s that ffn's swizzle makes XCD x CONSUME (4 MB/XCD, L2-resident).
// ---------------------------------------------------------------------------
__global__ __launch_bounds__(256) void k_inv(const unsigned int* __restrict__ VmW, const unsigned int* __restrict__ VmH,
                                             const short* __restrict__ GbF, unsigned short* __restrict__ s) {
    int t = threadIdx.x;
    int yt = blockIdx.x, wt = blockIdx.y, p = blockIdx.z;
    int wv = t >> 6, lane = t & 63, quad = lane >> 4, l15 = lane & 15;
    int ys = yt * 64 + wv * 16;
    const uint4* a2p = (const uint4*)(VmW + ((size_t)p * 512 + ys + l15) * 32 + quad * 8);
    unsigned int aw[8];
    {
        uint4 x0 = a2p[0], x1 = a2p[1];
        aw[0]=x0.x; aw[1]=x0.y; aw[2]=x0.z; aw[3]=x0.w;
        aw[4]=x1.x; aw[5]=x1.y; aw[6]=x1.z; aw[7]=x1.w;
    }
    short8 A2h, A2l; unzip8(aw, A2h, A2l);
    const short8* g1 = (const short8*)(GbF + (((yt * 4 + wv) * 64 + lane) << 4));
    short8 A1h = g1[0], A1l = g1[1];
    #pragma unroll
    for (int nt = 0; nt < 4; ++nt) {
        int wb = wt * 64 + nt * 16;
        const uint4* b1p = (const uint4*)(VmH + ((size_t)p * 512 + wb + l15) * 32 + quad * 8);
        unsigned int bw[8];
        uint4 x0 = b1p[0], x1 = b1p[1];
        bw[0]=x0.x; bw[1]=x0.y; bw[2]=x0.z; bw[3]=x0.w;
        bw[4]=x1.x; bw[5]=x1.y; bw[6]=x1.z; bw[7]=x1.w;
        short8 B1h, B1l; unzip8(bw, B1h, B1l);
        const short8* g2 = (const short8*)(GbF + (((wt * 4 + nt) * 64 + lane) << 4));
        short8 B2h = g2[0], B2l = g2[1];
        f32x4 acc = (f32x4){0.f,0.f,0.f,0.f};
        acc = MFMA16(A1h, B1h, acc);
        acc = MFMA16(A1l, B1h, acc);
        acc = MFMA16(A1h, B1l, acc);
        acc = MFMA16(A2h, B2h, acc);
        acc = MFMA16(A2l, B2h, acc);
        acc = MFMA16(A2h, B2l, acc);
        #pragma unroll
        for (int r = 0; r < 4; ++r)
            s[((size_t)p * 512 + ys + quad * 4 + r) * 512 + wb + l15] = bf16_rne(acc[r]);
    }
}

// ---------------------------------------------------------------------------
// MFMA FFN (single-tile, grid 4096): h(bf16) += gelu(W2.gelu(W1.s+b1)+b2).
// Tile swizzle: tile = (bid&7)*512 + (bid>>3). With round-robin block->XCD
// (XCD = bid%8), XCD x processes CONSECUTIVE tiles (y-slice [64x,64x+64)):
// adjacent 128-B bf16 halves of each 256-B sector merge in one XCD's L2 ->
// kills the 2x write amplification seen in R13 (WRITE 65 MB for 32 logical).
// GEMM1/GEMM2 2-term; RMW 2ch x 8px uint4; LDS 25856 B -> 6 blocks/CU.
// last==1: fused decoder to d_out.
// ---------------------------------------------------------------------------
union FfnSmem {
    unsigned int sB[64 * 33];   // 8448 B, staged bf16 s tile
    float oT[64 * 68];          // 17408 B, epilogue2 transpose tile
};

__global__ __launch_bounds__(256, 6) void k_ffn2m(const unsigned short* __restrict__ in, unsigned short* __restrict__ out,
                                                  const short* __restrict__ w1f, const float* __restrict__ b1v,
                                                  const short* __restrict__ w2f, const float* __restrict__ b2v,
                                                  const float* __restrict__ Wd, const float* __restrict__ bd,
                                                  float* __restrict__ dout, int last) {
    __shared__ __align__(16) FfnSmem u;
    __shared__ __align__(16) unsigned int tB[64 * 33];
    int t = threadIdx.x;
    int bid = blockIdx.x;
    int tile = (bid & 7) * 512 + (bid >> 3);   // XCD-local sequential tiles
    int pixBase = tile * 64;
    int lane15 = t & 15;
    int quad   = (t >> 4) & 3;
    int wv     = t >> 6;
    int row    = wv * 16 + lane15;
    int pix0 = (t & 7) * 8;                    // RMW pixel base (8 px -> uint4)
    int c0   = (t >> 3) * 2;                   // RMW channel base (2 ch)

    // ---- independent loads up front: h residual prefetch (uint4) + s tile ----
    uint4 hr[2];
    #pragma unroll
    for (int i = 0; i < 2; ++i)
        hr[i] = *(const uint4*)(out + (size_t)(c0 + i) * NPIX + pixBase + pix0);
    {
        int k  = t >> 3;                       // channel pair 0..31
        int po = t & 7;                        // pixel oct
        const uint4* r0 = (const uint4*)(in + (size_t)(2 * k) * NPIX + pixBase) + po;
        const uint4* r1 = (const uint4*)(in + (size_t)(2 * k + 1) * NPIX + pixBase) + po;
        uint4 a = *r0, b = *r1;
        unsigned int aw[4] = {a.x, a.y, a.z, a.w};
        unsigned int bw[4] = {b.x, b.y, b.z, b.w};
        #pragma unroll
        for (int i = 0; i < 4; ++i) {
            int pix = po * 8 + 2 * i;
            u.sB[pix * 33 + k]       = (aw[i] & 0xffffu) | (bw[i] << 16);
            u.sB[(pix + 1) * 33 + k] = (aw[i] >> 16) | (bw[i] & 0xffff0000u);
        }
    }

    short8 W1h[8], W1l[8];
    #pragma unroll
    for (int s8 = 0; s8 < 8; ++s8) {
        const short8* p = (const short8*)(w1f + (((size_t)s8 * 64 + (t & 63)) << 4));
        W1h[s8] = p[0]; W1l[s8] = p[1];
    }

    f32x4 acc[4];
    #pragma unroll
    for (int mt = 0; mt < 4; ++mt) acc[mt] = (f32x4){0.f, 0.f, 0.f, 0.f};

    __syncthreads();

    // ---- GEMM1: 2-term ----
    #pragma unroll
    for (int kc = 0; kc < 2; ++kc) {
        union { unsigned int w[4]; short8 v; } bb;
        #pragma unroll
        for (int i = 0; i < 4; ++i)
            bb.w[i] = u.sB[row * 33 + kc * 16 + quad * 4 + i];
        #pragma unroll
        for (int mt = 0; mt < 4; ++mt) {
            int s8 = mt * 2 + kc;
            acc[mt] = MFMA16(W1h[s8], bb.v, acc[mt]);
            acc[mt] = MFMA16(W1l[s8], bb.v, acc[mt]);
        }
    }

    // ---- epilogue1: gelu -> plain bf16 pairs -> tB ----
    #pragma unroll
    for (int mt = 0; mt < 4; ++mt) {
        const float* bp = b1v + mt * 16 + quad * 4;
        float g[4];
        #pragma unroll
        for (int r = 0; r < 4; ++r) g[r] = gelu_f(acc[mt][r] + bp[r]);
        int cp = (mt * 16 + quad * 4) >> 1;
        tB[row * 33 + cp]     = (unsigned int)bf16_rne(g[0]) | ((unsigned int)bf16_rne(g[1]) << 16);
        tB[row * 33 + cp + 1] = (unsigned int)bf16_rne(g[2]) | ((unsigned int)bf16_rne(g[3]) << 16);
        acc[mt] = (f32x4){0.f, 0.f, 0.f, 0.f};
    }

    short8 W2h[8], W2l[8];
    #pragma unroll
    for (int s8 = 0; s8 < 8; ++s8) {
        const short8* p = (const short8*)(w2f + (((size_t)s8 * 64 + (t & 63)) << 4));
        W2h[s8] = p[0]; W2l[s8] = p[1];
    }

    __syncthreads();   // tB visible; fences GEMM1 sB reads (oT may alias)

    // ---- GEMM2: 2-term ----
    #pragma unroll
    for (int kc = 0; kc < 2; ++kc) {
        union { unsigned int w[4]; short8 v; } bb;
        #pragma unroll
        for (int i = 0; i < 4; ++i)
            bb.w[i] = tB[row * 33 + kc * 16 + quad * 4 + i];
        #pragma unroll
        for (int mt = 0; mt < 4; ++mt) {
            int s8 = mt * 2 + kc;
            acc[mt] = MFMA16(W2h[s8], bb.v, acc[mt]);
            acc[mt] = MFMA16(W2l[s8], bb.v, acc[mt]);
        }
    }

    // ---- epilogue2: gelu -> oT (aliases sB) ----
    #pragma unroll
    for (int mt = 0; mt < 4; ++mt) {
        const float* bp = b2v + mt * 16 + quad * 4;
        #pragma unroll
        for (int r = 0; r < 4; ++r) {
            int o = mt * 16 + quad * 4 + r;
            u.oT[o * 68 + row] = gelu_f(acc[mt][r] + bp[r]);
        }
    }
    __syncthreads();

    if (!last) {
        // ---- h(bf16) += increment: 2 ch x 8 px, uint4 stores ----
        #pragma unroll
        for (int i = 0; i < 2; ++i) {
            int c = c0 + i;
            float4 g0 = *(const float4*)&u.oT[c * 68 + pix0];
            float4 g1 = *(const float4*)&u.oT[c * 68 + pix0 + 4];
            unsigned int w[4] = {hr[i].x, hr[i].y, hr[i].z, hr[i].w};
            float f[8];
            f[0] = bf16_tof((unsigned short)(w[0] & 0xffffu)) + g0.x;
            f[1] = bf16_tof((unsigned short)(w[0] >> 16))     + g0.y;
            f[2] = bf16_tof((unsigned short)(w[1] & 0xffffu)) + g0.z;
            f[3] = bf16_tof((unsigned short)(w[1] >> 16))     + g0.w;
            f[4] = bf16_tof((unsigned short)(w[2] & 0xffffu)) + g1.x;
            f[5] = bf16_tof((unsigned short)(w[2] >> 16))     + g1.y;
            f[6] = bf16_tof((unsigned short)(w[3] & 0xffffu)) + g1.z;
            f[7] = bf16_tof((unsigned short)(w[3] >> 16))     + g1.w;
            uint4 o;
            o.x = (unsigned int)bf16_rne(f[0]) | ((unsigned int)bf16_rne(f[1]) << 16);
            o.y = (unsigned int)bf16_rne(f[2]) | ((unsigned int)bf16_rne(f[3]) << 16);
            o.z = (unsigned int)bf16_rne(f[4]) | ((unsigned int)bf16_rne(f[5]) << 16);
            o.w = (unsigned int)bf16_rne(f[6]) | ((unsigned int)bf16_rne(f[7]) << 16);
            *(uint4*)(out + (size_t)c * NPIX + pixBase + pix0) = o;
        }
    } else {
        // ---- fused decoder: dout = sum_c Wd[c]*(hres+gv) + bd ----
        float part[8] = {0.f,0.f,0.f,0.f,0.f,0.f,0.f,0.f};
        #pragma unroll
        for (int i = 0; i < 2; ++i) {
            int c = c0 + i;
            float wd = Wd[c];
            float4 g0 = *(const float4*)&u.oT[c * 68 + pix0];
            float4 g1 = *(const float4*)&u.oT[c * 68 + pix0 + 4];
            unsigned int w[4] = {hr[i].x, hr[i].y, hr[i].z, hr[i].w};
            part[0] += wd * (bf16_tof((unsigned short)(w[0] & 0xffffu)) + g0.x);
            part[1] += wd * (bf16_tof((unsigned short)(w[0] >> 16))     + g0.y);
            part[2] += wd * (bf16_tof((unsigned short)(w[1] & 0xffffu)) + g0.z);
            part[3] += wd * (bf16_tof((unsigned short)(w[1] >> 16))     + g0.w);
            part[4] += wd * (bf16_tof((unsigned short)(w[2] & 0xffffu)) + g1.x);
            part[5] += wd * (bf16_tof((unsigned short)(w[2] >> 16))     + g1.y);
            part[6] += wd * (bf16_tof((unsigned short)(w[3] & 0xffffu)) + g1.z);
            part[7] += wd * (bf16_tof((unsigned short)(w[3] >> 16))     + g1.w);
        }
        __syncthreads();   // tB GEMM2 reads done before aliasing as red
        float* red = (float*)tB;               // 32 grp x 65 stride: 8320 B fits tB
        int g = t >> 3;                        // channel-pair group 0..31
        #pragma unroll
        for (int j = 0; j < 8; ++j)
            red[g * 65 + pix0 + j] = part[j];
        __syncthreads();
        if (t < 64) {
            float sum = bd[0];
            #pragma unroll
            for (int gg = 0; gg < 32; ++gg)
                sum += red[gg * 65 + t];
            dout[pixBase + t] = sum;
        }
    }
}

extern "C" void kernel_launch(void* const* d_in, const int* in_sizes, int n_in,
                              void* d_out, int out_size, void* d_ws, size_t ws_size,
                              hipStream_t stream) {
    (void)in_sizes; (void)n_in; (void)out_size; (void)ws_size;
    const float* u   = (const float*)d_in[0];
    const float* xc  = (const float*)d_in[1];
    const float* We  = (const float*)d_in[2];
    const float* be  = (const float*)d_in[3];
    const float* W1  = (const float*)d_in[4];
    const float* b1  = (const float*)d_in[5];
    const float* W2  = (const float*)d_in[6];
    const float* b2  = (const float*)d_in[7];
    const float* Are = (const float*)d_in[8];
    const float* Aim = (const float*)d_in[9];
    const float* Wd  = (const float*)d_in[10];
    const float* bd  = (const float*)d_in[11];

    // workspace layout, ~93 MB used
    char* ws = (char*)d_ws;
    unsigned short* h = (unsigned short*)ws;                  // 32 MB (bf16)
    unsigned short* s = (unsigned short*)(ws + (size_t)33554432); // 32 MB (bf16)
    float* VfH = (float*)(ws + (size_t)67108864);             // 4 MB: [64][32][512]
    float* VfW = VfH + (size_t)1048576;                       // 4 MB
    unsigned int* VmH = (unsigned int*)(VfW + 1048576);       // 4 MB split-packed
    unsigned int* VmW = VmH + (size_t)1048576;                // 4 MB
    short* FbB = (short*)(VmW + 1048576);                     // 64 KB
    short* GbF = FbB + 32768;                                 // 64 KB
    short* Am  = GbF + 32768;                                 // 6 MB
    short* Wpk = Am  + (size_t)65536 * 48;                    // 128 KB

    k_setup<<<1312, 256, 0, stream>>>(W1, W2, Are, Aim, u, xc, We, be,
                                      FbB, GbF, Wpk, Am, h);

    for (int l = 0; l < 4; ++l) {
        k_fwd<<<dim3(64, 8, 2), 256, 0, stream>>>(h, FbB, VfH, VfW);
        k_mix2<<<512, 256, 0, stream>>>(VfH, VfW, Am + (size_t)(l * 2) * ASLAB, VmH, VmW);
        k_inv<<<dim3(8, 8, 64), 256, 0, stream>>>(VmW, VmH, GbF, s);
        k_ffn2m<<<4096, 256, 0, stream>>>(s, h,
                                          Wpk + (size_t)(l * 2 + 0) * 8192, b1 + (size_t)l * 64,
                                          Wpk + (size_t)(l * 2 + 1) * 8192, b2 + (size_t)l * 64,
                                          Wd, bd, (float*)d_out, (l == 3) ? 1 : 0);
    }
}

// Round 15
// 489.351 us; speedup vs baseline: 1.8047x; 1.0184x over previous
//
#include <hip/hip_runtime.h>

#define NPIX (512*512)

typedef __attribute__((ext_vector_type(8))) short short8;   // 8 bf16 in 4 VGPRs
typedef __attribute__((ext_vector_type(4))) float f32x4;    // MFMA accumulator

#define MFMA16(A, B, C) __builtin_amdgcn_mfma_f32_16x16x32_bf16((A), (B), (C), 0, 0, 0)

// JAX gelu(approximate=True): x * sigmoid(2*sqrt(2/pi)*(x+0.044715x^3)); inf-safe.
__device__ __forceinline__ float gelu_f(float x) {
    return x / (1.0f + __expf(-1.5957691216057308f * (x + 0.044715f * x * x * x)));
}

// f32 -> bf16 bits (RNE)
__device__ __forceinline__ unsigned short bf16_rne(float x) {
    unsigned int b = __float_as_uint(x);
    unsigned int r = b + 0x7fffu + ((b >> 16) & 1u);
    return (unsigned short)(r >> 16);
}
__device__ __forceinline__ float bf16_tof(unsigned short h) {
    return __uint_as_float(((unsigned int)h) << 16);
}
__device__ __forceinline__ unsigned int bf16_split_pack(float x) {
    unsigned short hi = bf16_rne(x);
    unsigned short lo = bf16_rne(x - bf16_tof(hi));
    return (unsigned int)hi | ((unsigned int)lo << 16);
}
// unzip 8 split-packed u32 (hi|lo<<16 per elem) -> hi-short8 / lo-short8
__device__ __forceinline__ void unzip8(const unsigned int* w, short8& h, short8& l) {
    union { unsigned int u[4]; short8 v; } hh, ll;
    #pragma unroll
    for (int i = 0; i < 4; ++i) {
        hh.u[i] = (w[2*i] & 0xffffu) | (w[2*i+1] << 16);
        ll.u[i] = (w[2*i] >> 16) | (w[2*i+1] & 0xffff0000u);
    }
    h = hh.v; l = ll.v;
}

#define ASLAB ((size_t)16 * 4 * 2 * 64 * 48)   // shorts per (l,ax) in Am

// ---------------------------------------------------------------------------
// Merged setup + encoder: blocks 0..15 basis tables, 16..31 FFN weights,
// 32..287 spectral A-weights, 288..1311 encoder (h stored bf16).
// ---------------------------------------------------------------------------
__global__ __launch_bounds__(256) void k_setup(const float* __restrict__ W1, const float* __restrict__ W2,
                                               const float* __restrict__ Are, const float* __restrict__ Aim,
                                               const float* __restrict__ u, const float* __restrict__ xc,
                                               const float* __restrict__ We, const float* __restrict__ be,
                                               short* __restrict__ FbB, short* __restrict__ GbF,
                                               short* __restrict__ Wpk, short* __restrict__ Am,
                                               unsigned short* __restrict__ h) {
    int b = blockIdx.x;
    int t = threadIdx.x;
    if (b < 16) {
        int id = b * 256 + t;
        int lane = id & 63;
        int quad = lane >> 4, l15 = lane & 15;
        short* dst;
        int n0, nstep, o0, ostep;
        float wscale = 1.0f;
        if (id < 2048) {
            int nt = (id >> 6) & 1, kc = id >> 7;
            dst = FbB + id * 16;
            n0 = kc * 32 + quad * 8; nstep = 1;
            o0 = nt * 16 + l15;      ostep = 0;
        } else {
            int id2 = id - 2048;
            dst = GbF + id2 * 16;
            int tt = id2 >> 6;
            n0 = tt * 16 + l15;      nstep = 0;
            o0 = quad * 8;           ostep = 1;
            wscale = 1.0f / 512.0f;
        }
        #pragma unroll
        for (int j = 0; j < 8; ++j) {
            int n = n0 + nstep * j;
            int o = o0 + ostep * j;
            int m = o >> 1, ri = o & 1;
            int k = (n * m) & 511;
            float sv, cv;
            sincosf(6.283185307179586f * (1.0f / 512.0f) * (float)k, &sv, &cv);
            float v = ri ? -sv : cv;
            if (id >= 2048) v *= (m == 0 ? 1.0f : 2.0f) * wscale;
            unsigned short hi = bf16_rne(v);
            dst[j]     = (short)hi;
            dst[8 + j] = (short)bf16_rne(v - bf16_tof(hi));
        }
    } else if (b < 32) {
        int tid = (b - 16) * 256 + t;
        int lane = tid & 63;
        int kc = (tid >> 6) & 1;
        int mt = (tid >> 7) & 3;
        int wg = tid >> 9;
        int layer = wg >> 1, which = wg & 1;
        const float* Wsrc = (which ? W2 : W1) + (size_t)layer * 4096;
        int o  = mt * 16 + (lane & 15);
        int c0 = kc * 32 + ((lane >> 4) & 3) * 8;
        short* dst = Wpk + (size_t)tid * 16;
        #pragma unroll
        for (int j = 0; j < 8; ++j) {
            float x = Wsrc[o * 64 + c0 + j];
            unsigned short hi = bf16_rne(x);
            dst[j]     = (short)hi;
            dst[8 + j] = (short)bf16_rne(x - bf16_tof(hi));
        }
    } else if (b < 288) {
        int id = (b - 32) * 256 + t;
        int lane = id & 63;
        int kc  = (id >> 6) & 1;
        int mt  = (id >> 7) & 3;
        int m   = (id >> 9) & 15;
        int lax = id >> 13;
        int l = lax >> 1, ax = lax & 1;
        int o  = mt * 16 + (lane & 15);
        int i0 = kc * 32 + ((lane >> 4) & 3) * 8;
        short* dst = Am + (size_t)id * 48;
        #pragma unroll
        for (int j = 0; j < 8; ++j) {
            size_t src = (((size_t)(l * 64 + o) * 64 + (i0 + j)) * 16 + m) * 2 + ax;
            float ar = Are[src], ai = Aim[src];
            unsigned short hh;
            hh = bf16_rne(ar);  dst[j]      = (short)hh; dst[8 + j]  = (short)bf16_rne(ar - bf16_tof(hh));
            hh = bf16_rne(ai);  dst[16 + j] = (short)hh; dst[24 + j] = (short)bf16_rne(ai - bf16_tof(hh));
            hh = bf16_rne(-ai); dst[32 + j] = (short)hh; dst[40 + j] = (short)bf16_rne(-ai - bf16_tof(hh));
        }
    } else {
        // encoder: h[p][pix] = bf16(We.x + be)
        int pix = (b - 288) * 256 + t;
        float x0 = xc[pix], x1 = xc[NPIX + pix], uu = u[pix];
        #pragma unroll 8
        for (int p = 0; p < 64; ++p) {
            float v = We[p * 3] * x0 + We[p * 3 + 1] * x1 + We[p * 3 + 2] * uu + be[p];
            h[(size_t)p * NPIX + pix] = bf16_rne(v);
        }
    }
}

// ---------------------------------------------------------------------------
// Merged forward DFT, both axes, h in bf16 (B-frag direct reinterpret; A-side
// basis split -> 2-term MFMA). grid(64 p, 8 ntile, 2 axis).
// ---------------------------------------------------------------------------
__global__ __launch_bounds__(256) void k_fwd(const unsigned short* __restrict__ h, const short* __restrict__ FbB,
                                             float* __restrict__ VfH, float* __restrict__ VfW) {
    int t = threadIdx.x;
    int p = blockIdx.x, ntb = blockIdx.y, axis = blockIdx.z;
    int wv = t >> 6, lane = t & 63, quad = lane >> 4, l15 = lane & 15;
    int n = ntb * 64 + wv * 16 + l15;
    f32x4 acc[2];
    acc[0] = (f32x4){0.f,0.f,0.f,0.f}; acc[1] = (f32x4){0.f,0.f,0.f,0.f};
    #pragma unroll 4
    for (int kc = 0; kc < 16; ++kc) {
        int kb = kc * 32 + quad * 8;
        short8 Bv;
        if (axis == 0) {
            const unsigned short* hp = h + ((size_t)p * 512 + kb) * 512 + n;
            #pragma unroll
            for (int j = 0; j < 8; ++j) Bv[j] = (short)hp[(size_t)j * 512];
        } else {
            const unsigned short* hp = h + ((size_t)p * 512 + n) * 512 + kb;
            Bv = *(const short8*)hp;
        }
        #pragma unroll
        for (int mt = 0; mt < 2; ++mt) {
            const short8* ap = (const short8*)(FbB + (((kc * 2 + mt) * 64 + lane) << 4));
            short8 Ah = ap[0], Al = ap[1];
            acc[mt] = MFMA16(Ah, Bv, acc[mt]);
            acc[mt] = MFMA16(Al, Bv, acc[mt]);
        }
    }
    float* vp = (axis ? VfW : VfH) + (size_t)p * 32 * 512;
    #pragma unroll
    for (int mt = 0; mt < 2; ++mt)
        #pragma unroll
        for (int r = 0; r < 4; ++r)
            vp[(size_t)(mt * 16 + quad * 4 + r) * 512 + n] = acc[mt][r];
}

// ---------------------------------------------------------------------------
// Merged mode mixing, both axes. Epilogue writes Vm SPLIT-PACKED u32.
// grid 512 (axis = bid>>8; m = bid&15, otile = (bid>>4)&15), block 256.
// ---------------------------------------------------------------------------
__global__ __launch_bounds__(256) void k_mix2(const float* __restrict__ VfH, const float* __restrict__ VfW,
                                              const short* __restrict__ AmL,
                                              unsigned int* __restrict__ VmH, unsigned int* __restrict__ VmW) {
    __shared__ unsigned int BT[2 * 64 * 33];
    int bid = blockIdx.x;
    int axis = bid >> 8;
    int m  = bid & 15;
    int ot = (bid >> 4) & 15;
    const float* Vf = axis ? VfW : VfH;
    unsigned int* Vm = axis ? VmW : VmH;
    const short* Am = AmL + (size_t)axis * ASLAB;
    int t = threadIdx.x;
    #pragma unroll
    for (int it = 0; it < 16; ++it) {
        int idx = it * 256 + t;
        int oth = idx & 31, ri = (idx >> 5) & 1, i = idx >> 6;
        float v = Vf[((size_t)i * 32 + m * 2 + ri) * 512 + ot * 32 + oth];
        BT[(ri * 64 + i) * 33 + oth] = bf16_split_pack(v);
    }
    __syncthreads();
    int wv = t >> 6, lane = t & 63, quad = lane >> 4, l15 = lane & 15;
    int nt = wv & 1, mtp = wv >> 1;
    f32x4 aR[2], aI[2];
    aR[0]=(f32x4){0.f,0.f,0.f,0.f}; aR[1]=aR[0]; aI[0]=aR[0]; aI[1]=aR[0];
    #pragma unroll
    for (int kc = 0; kc < 2; ++kc) {
        short8 Brh, Brl, Bih, Bil;
        #pragma unroll
        for (int j = 0; j < 8; ++j) {
            int i = kc * 32 + quad * 8 + j;
            unsigned int br = BT[i * 33 + nt * 16 + l15];
            unsigned int bi = BT[(64 + i) * 33 + nt * 16 + l15];
            Brh[j] = (short)(br & 0xffffu); Brl[j] = (short)(br >> 16);
            Bih[j] = (short)(bi & 0xffffu); Bil[j] = (short)(bi >> 16);
        }
        #pragma unroll
        for (int mi = 0; mi < 2; ++mi) {
            int mt = mtp * 2 + mi;
            const short8* ap = (const short8*)(Am + ((size_t)(((m * 4 + mt) * 2 + kc) * 64 + lane)) * 48);
            short8 Arh = ap[0], Arl = ap[1], Aih = ap[2], Ail = ap[3], Anh = ap[4], Anl = ap[5];
            aR[mi] = MFMA16(Arh, Brh, aR[mi]);
            aR[mi] = MFMA16(Arl, Brh, aR[mi]);
            aR[mi] = MFMA16(Arh, Brl, aR[mi]);
            aR[mi] = MFMA16(Anh, Bih, aR[mi]);
            aR[mi] = MFMA16(Anl, Bih, aR[mi]);
            aR[mi] = MFMA16(Anh, Bil, aR[mi]);
            aI[mi] = MFMA16(Arh, Bih, aI[mi]);
            aI[mi] = MFMA16(Arl, Bih, aI[mi]);
            aI[mi] = MFMA16(Arh, Bil, aI[mi]);
            aI[mi] = MFMA16(Aih, Brh, aI[mi]);
            aI[mi] = MFMA16(Ail, Brh, aI[mi]);
            aI[mi] = MFMA16(Aih, Brl, aI[mi]);
        }
    }
    int oth = ot * 32 + nt * 16 + l15;
    #pragma unroll
    for (int mi = 0; mi < 2; ++mi) {
        int o = (mtp * 2 + mi) * 16 + quad * 4;
        #pragma unroll
        for (int r = 0; r < 4; ++r) {
            uint2 v;
            v.x = bf16_split_pack(aR[mi][r]);
            v.y = bf16_split_pack(aI[mi][r]);
            *(uint2*)(Vm + ((size_t)(o + r) * 512 + oth) * 32 + m * 2) = v;
        }
    }
}

// ---------------------------------------------------------------------------
// Fused inverse DFT (both axes) -> s as PLAIN BF16 (2 B).
// grid(8 yt, 8 wt, 64 p).
// ---------------------------------------------------------------------------
__global__ __launch_bounds__(256) void k_inv(const unsigned int* __restrict__ VmW, const unsigned int* __restrict__ VmH,
                                             const short* __restrict__ GbF, unsigned short* __restrict__ s) {
    int t = threadIdx.x;
    int yt = blockIdx.x, wt = blockIdx.y, p = blockIdx.z;
    int wv = t >> 6, lane = t & 63, quad = lane >> 4, l15 = lane & 15;
    int ys = yt * 64 + wv * 16;
    const uint4* a2p = (const uint4*)(VmW + ((size_t)p * 512 + ys + l15) * 32 + quad * 8);
    unsigned int aw[8];
    {
        uint4 x0 = a2p[0], x1 = a2p[1];
        aw[0]=x0.x; aw[1]=x0.y; aw[2]=x0.z; aw[3]=x0.w;
        aw[4]=x1.x; aw[5]=x1.y; aw[6]=x1.z; aw[7]=x1.w;
    }
    short8 A2h, A2l; unzip8(aw, A2h, A2l);
    const short8* g1 = (const short8*)(GbF + (((yt * 4 + wv) * 64 + lane) << 4));
    short8 A1h = g1[0], A1l = g1[1];
    #pragma unroll
    for (int nt = 0; nt < 4; ++nt) {
        int wb = wt * 64 + nt * 16;
        const uint4* b1p = (const uint4*)(VmH + ((size_t)p * 512 + wb + l15) * 32 + quad * 8);
        unsigned int bw[8];
        uint4 x0 = b1p[0], x1 = b1p[1];
        bw[0]=x0.x; bw[1]=x0.y; bw[2]=x0.z; bw[3]=x0.w;
        bw[4]=x1.x; bw[5]=x1.y; bw[6]=x1.z; bw[7]=x1.w;
        short8 B1h, B1l; unzip8(bw, B1h, B1l);
        const short8* g2 = (const short8*)(GbF + (((wt * 4 + nt) * 64 + lane) << 4));
        short8 B2h = g2[0], B2l = g2[1];
        f32x4 acc = (f32x4){0.f,0.f,0.f,0.f};
        acc = MFMA16(A1h, B1h, acc);
        acc = MFMA16(A1l, B1h, acc);
        acc = MFMA16(A1h, B1l, acc);
        acc = MFMA16(A2h, B2h, acc);
        acc = MFMA16(A2l, B2h, acc);
        acc = MFMA16(A2h, B2l, acc);
        #pragma unroll
        for (int r = 0; r < 4; ++r)
            s[((size_t)p * 512 + ys + quad * 4 + r) * 512 + wb + l15] = bf16_rne(acc[r]);
    }
}

// ---------------------------------------------------------------------------
// MFMA FFN, 128-PIXEL tile (grid 2048): h(bf16) += gelu(W2.gelu(W1.s+b1)+b2).
// 128 px x 2 B = 256 B per channel row = one FULL HBM sector written by 16
// lanes of one wave in one instruction -> no partial-sector write
// amplification (R13/R14: 65 MB written for 32 logical; XCD swizzle did NOT
// fix it -> fix it within-wave instead).
// Waves: wv handles n-slices {wv*32+0..15, wv*32+16..31}; acc[2][4].
// sB/tB stride-33 (proven); oT is BF16 stride-136 u16 (16-B-aligned uint4
// reads), aliases sB. LDS 34304 B -> 4 blocks/CU.
// last==1: fused decoder to d_out.
// ---------------------------------------------------------------------------
union FfnSmem {
    unsigned int  sB[128 * 33];     // 16896 B, staged bf16 s tile [pix][ch-pair]
    unsigned short oTb[64 * 136];   // 17408 B, epilogue2 bf16 transpose tile
};

__global__ __launch_bounds__(256, 4) void k_ffn2m(const unsigned short* __restrict__ in, unsigned short* __restrict__ out,
                                                  const short* __restrict__ w1f, const float* __restrict__ b1v,
                                                  const short* __restrict__ w2f, const float* __restrict__ b2v,
                                                  const float* __restrict__ Wd, const float* __restrict__ bd,
                                                  float* __restrict__ dout, int last) {
    __shared__ __align__(16) FfnSmem u;
    __shared__ __align__(16) unsigned int tB[128 * 33];
    int t = threadIdx.x;
    int pixBase = blockIdx.x * 128;
    int lane15 = t & 15;
    int quad   = (t >> 4) & 3;
    int wv     = t >> 6;
    int k  = t >> 3;                           // staging channel pair 0..31
    int po = t & 7;                            // staging pixel oct (first half)
    int oct = t & 15;                          // store pixel oct 0..15
    int cg  = t >> 4;                          // store channel group 0..15

    // ---- independent loads up front: h residual prefetch + s tile ----
    uint4 hr[4];
    #pragma unroll
    for (int j = 0; j < 4; ++j) {
        int c = cg + 16 * j;
        hr[j] = *(const uint4*)(out + (size_t)c * NPIX + pixBase + oct * 8);
    }
    #pragma unroll
    for (int half = 0; half < 2; ++half) {
        int so = (po + half * 8) * 8;          // pixel base 0..120
        uint4 a = *(const uint4*)(in + (size_t)(2 * k) * NPIX + pixBase + so);
        uint4 b = *(const uint4*)(in + (size_t)(2 * k + 1) * NPIX + pixBase + so);
        unsigned int aw[4] = {a.x, a.y, a.z, a.w};
        unsigned int bw[4] = {b.x, b.y, b.z, b.w};
        #pragma unroll
        for (int i = 0; i < 4; ++i) {
            int pix = so + 2 * i;
            u.sB[pix * 33 + k]       = (aw[i] & 0xffffu) | (bw[i] << 16);
            u.sB[(pix + 1) * 33 + k] = (aw[i] >> 16) | (bw[i] & 0xffff0000u);
        }
    }

    short8 W1h[8], W1l[8];
    #pragma unroll
    for (int s8 = 0; s8 < 8; ++s8) {
        const short8* p = (const short8*)(w1f + (((size_t)s8 * 64 + (t & 63)) << 4));
        W1h[s8] = p[0]; W1l[s8] = p[1];
    }

    f32x4 acc[2][4];
    #pragma unroll
    for (int ns = 0; ns < 2; ++ns)
        #pragma unroll
        for (int mt = 0; mt < 4; ++mt) acc[ns][mt] = (f32x4){0.f, 0.f, 0.f, 0.f};

    __syncthreads();

    // ---- GEMM1: 2-term, 2 n-slices ----
    #pragma unroll
    for (int ns = 0; ns < 2; ++ns) {
        int row = wv * 32 + ns * 16 + lane15;
        #pragma unroll
        for (int kc = 0; kc < 2; ++kc) {
            union { unsigned int w[4]; short8 v; } bb;
            #pragma unroll
            for (int i = 0; i < 4; ++i)
                bb.w[i] = u.sB[row * 33 + kc * 16 + quad * 4 + i];
            #pragma unroll
            for (int mt = 0; mt < 4; ++mt) {
                int s8 = mt * 2 + kc;
                acc[ns][mt] = MFMA16(W1h[s8], bb.v, acc[ns][mt]);
                acc[ns][mt] = MFMA16(W1l[s8], bb.v, acc[ns][mt]);
            }
        }
    }

    // ---- epilogue1: gelu -> bf16 pairs -> tB ----
    #pragma unroll
    for (int ns = 0; ns < 2; ++ns) {
        int row = wv * 32 + ns * 16 + lane15;
        #pragma unroll
        for (int mt = 0; mt < 4; ++mt) {
            const float* bp = b1v + mt * 16 + quad * 4;
            float g[4];
            #pragma unroll
            for (int r = 0; r < 4; ++r) g[r] = gelu_f(acc[ns][mt][r] + bp[r]);
            int cp = (mt * 16 + quad * 4) >> 1;
            tB[row * 33 + cp]     = (unsigned int)bf16_rne(g[0]) | ((unsigned int)bf16_rne(g[1]) << 16);
            tB[row * 33 + cp + 1] = (unsigned int)bf16_rne(g[2]) | ((unsigned int)bf16_rne(g[3]) << 16);
            acc[ns][mt] = (f32x4){0.f, 0.f, 0.f, 0.f};
        }
    }

    short8 W2h[8], W2l[8];
    #pragma unroll
    for (int s8 = 0; s8 < 8; ++s8) {
        const short8* p = (const short8*)(w2f + (((size_t)s8 * 64 + (t & 63)) << 4));
        W2h[s8] = p[0]; W2l[s8] = p[1];
    }

    __syncthreads();   // tB visible; fences GEMM1 sB reads (oTb may alias)

    // ---- GEMM2: 2-term, 2 n-slices ----
    #pragma unroll
    for (int ns = 0; ns < 2; ++ns) {
        int row = wv * 32 + ns * 16 + lane15;
        #pragma unroll
        for (int kc = 0; kc < 2; ++kc) {
            union { unsigned int w[4]; short8 v; } bb;
            #pragma unroll
            for (int i = 0; i < 4; ++i)
                bb.w[i] = tB[row * 33 + kc * 16 + quad * 4 + i];
            #pragma unroll
            for (int mt = 0; mt < 4; ++mt) {
                int s8 = mt * 2 + kc;
                acc[ns][mt] = MFMA16(W2h[s8], bb.v, acc[ns][mt]);
                acc[ns][mt] = MFMA16(W2l[s8], bb.v, acc[ns][mt]);
            }
        }
    }

    // ---- epilogue2: gelu -> bf16 oTb (aliases sB) ----
    #pragma unroll
    for (int ns = 0; ns < 2; ++ns) {
        int px = wv * 32 + ns * 16 + lane15;
        #pragma unroll
        for (int mt = 0; mt < 4; ++mt) {
            const float* bp = b2v + mt * 16 + quad * 4;
            #pragma unroll
            for (int r = 0; r < 4; ++r) {
                int c = mt * 16 + quad * 4 + r;
                u.oTb[c * 136 + px] = bf16_rne(gelu_f(acc[ns][mt][r] + bp[r]));
            }
        }
    }
    __syncthreads();

    if (!last) {
        // ---- h(bf16) += increment: (c,oct) units, uint4, full 256-B sectors/wave ----
        #pragma unroll
        for (int j = 0; j < 4; ++j) {
            int c = cg + 16 * j;
            uint4 gv = *(const uint4*)&u.oTb[c * 136 + oct * 8];
            unsigned int hw[4] = {hr[j].x, hr[j].y, hr[j].z, hr[j].w};
            unsigned int gw[4] = {gv.x, gv.y, gv.z, gv.w};
            uint4 o;
            unsigned int* op = &o.x;
            #pragma unroll
            for (int i = 0; i < 4; ++i) {
                float f0 = bf16_tof((unsigned short)(hw[i] & 0xffffu)) + bf16_tof((unsigned short)(gw[i] & 0xffffu));
                float f1 = bf16_tof((unsigned short)(hw[i] >> 16))     + bf16_tof((unsigned short)(gw[i] >> 16));
                op[i] = (unsigned int)bf16_rne(f0) | ((unsigned int)bf16_rne(f1) << 16);
            }
            *(uint4*)(out + (size_t)c * NPIX + pixBase + oct * 8) = o;
        }
    } else {
        // ---- fused decoder: dout = sum_c Wd[c]*(hres+gv) + bd (red aliases tB) ----
        float part[8] = {0.f,0.f,0.f,0.f,0.f,0.f,0.f,0.f};
        #pragma unroll
        for (int j = 0; j < 4; ++j) {
            int c = cg + 16 * j;
            float wd = Wd[c];
            uint4 gv = *(const uint4*)&u.oTb[c * 136 + oct * 8];
            unsigned int hw[4] = {hr[j].x, hr[j].y, hr[j].z, hr[j].w};
            unsigned int gw[4] = {gv.x, gv.y, gv.z, gv.w};
            #pragma unroll
            for (int i = 0; i < 4; ++i) {
                part[2*i]   += wd * (bf16_tof((unsigned short)(hw[i] & 0xffffu)) + bf16_tof((unsigned short)(gw[i] & 0xffffu)));
                part[2*i+1] += wd * (bf16_tof((unsigned short)(hw[i] >> 16))     + bf16_tof((unsigned short)(gw[i] >> 16)));
            }
        }
        float* red = (float*)tB;               // 16 grp x 132 stride x 4 B = 8448 B fits tB
        #pragma unroll
        for (int i = 0; i < 8; ++i)
            red[cg * 132 + oct * 8 + i] = part[i];
        __syncthreads();
        if (t < 128) {
            float sum = bd[0];
            #pragma unroll
            for (int gg = 0; gg < 16; ++gg)
                sum += red[gg * 132 + t];
            dout[pixBase + t] = sum;
        }
    }
}

extern "C" void kernel_launch(void* const* d_in, const int* in_sizes, int n_in,
                              void* d_out, int out_size, void* d_ws, size_t ws_size,
                              hipStream_t stream) {
    (void)in_sizes; (void)n_in; (void)out_size; (void)ws_size;
    const float* u   = (const float*)d_in[0];
    const float* xc  = (const float*)d_in[1];
    const float* We  = (const float*)d_in[2];
    const float* be  = (const float*)d_in[3];
    const float* W1  = (const float*)d_in[4];
    const float* b1  = (const float*)d_in[5];
    const float* W2  = (const float*)d_in[6];
    const float* b2  = (const float*)d_in[7];
    const float* Are = (const float*)d_in[8];
    const float* Aim = (const float*)d_in[9];
    const float* Wd  = (const float*)d_in[10];
    const float* bd  = (const float*)d_in[11];

    // workspace layout, ~93 MB used
    char* ws = (char*)d_ws;
    unsigned short* h = (unsigned short*)ws;                  // 32 MB (bf16)
    unsigned short* s = (unsigned short*)(ws + (size_t)33554432); // 32 MB (bf16)
    float* VfH = (float*)(ws + (size_t)67108864);             // 4 MB: [64][32][512]
    float* VfW = VfH + (size_t)1048576;                       // 4 MB
    unsigned int* VmH = (unsigned int*)(VfW + 1048576);       // 4 MB split-packed
    unsigned int* VmW = VmH + (size_t)1048576;                // 4 MB
    short* FbB = (short*)(VmW + 1048576);                     // 64 KB
    short* GbF = FbB + 32768;                                 // 64 KB
    short* Am  = GbF + 32768;                                 // 6 MB
    short* Wpk = Am  + (size_t)65536 * 48;                    // 128 KB

    k_setup<<<1312, 256, 0, stream>>>(W1, W2, Are, Aim, u, xc, We, be,
                                      FbB, GbF, Wpk, Am, h);

    for (int l = 0; l < 4; ++l) {
        k_fwd<<<dim3(64, 8, 2), 256, 0, stream>>>(h, FbB, VfH, VfW);
        k_mix2<<<512, 256, 0, stream>>>(VfH, VfW, Am + (size_t)(l * 2) * ASLAB, VmH, VmW);
        k_inv<<<dim3(8, 8, 64), 256, 0, stream>>>(VmW, VmH, GbF, s);
        k_ffn2m<<<2048, 256, 0, stream>>>(s, h,
                                          Wpk + (size_t)(l * 2 + 0) * 8192, b1 + (size_t)l * 64,
                                          Wpk + (size_t)(l * 2 + 1) * 8192, b2 + (size_t)l * 64,
                                          Wd, bd, (float*)d_out, (l == 3) ? 1 : 0);
    }
}